// Round 7
// baseline (435.837 us; speedup 1.0000x reference)
//
#include <hip/hip_runtime.h>
#include <hip/hip_cooperative_groups.h>

#define NN 10000
#define NE 320000
#define MP 10112        // 158*64 padded rows
#define BN_EPS 1e-5f

#define NRANGE 64       // row-ranges (160 rows each)
#define BROWS 160
#define NBUCK 128       // row-range x j-half buckets
#define HBITS 5120      // bits per j-half
#define HWORDS 160      // words per j-half row
#define SUBCAP 128      // keys per (bucket, block) sub-chunk (mean ~39)
#define EPB   5000      // edges per bucketize block (64*5000 = NE exact)

typedef __attribute__((ext_vector_type(8))) short short8;
typedef __attribute__((ext_vector_type(4))) float f32x4;
typedef unsigned short u16;

// ---------------- helpers ----------------
__device__ __forceinline__ void split1(float v, u16& h, u16& l) {
    unsigned int u = __float_as_uint(v);
    h = (u16)(u >> 16);
    float hf = __uint_as_float(u & 0xFFFF0000u);
    l = (u16)(__float_as_uint(v - hf) >> 16);
}

__device__ __forceinline__ void gll16(const void* g, void* l) {
    __builtin_amdgcn_global_load_lds(
        (const __attribute__((address_space(1))) unsigned int*)g,
        (__attribute__((address_space(3))) unsigned int*)l, 16, 0, 0);
}

// ---------------- splitW (proven): Wt[n][k] = split(W[k][n]) ----------------
__device__ void splitW_dev(const float* __restrict__ W, int K, int N, int Kp, int Np,
                           u16* __restrict__ Wt, int bx, int by, char* smem) {
    float (*tile)[65] = (float(*)[65])smem;
    int t = threadIdx.x;
    int bk = bx * 64, bn = by * 64;
    #pragma unroll
    for (int p = 0; p < 4; ++p) {
        int kk = (t >> 4) + p * 16;
        int nc = (t & 15) * 4;
        int k = bk + kk;
        float4 v = {0.f, 0.f, 0.f, 0.f};
        if (k < K && bn + nc + 3 < N)
            v = *(const float4*)&W[(size_t)k * N + bn + nc];
        tile[kk][nc] = v.x; tile[kk][nc + 1] = v.y;
        tile[kk][nc + 2] = v.z; tile[kk][nc + 3] = v.w;
    }
    __syncthreads();
    int nn = t >> 2;
    int kk0 = (t & 3) * 16;
    u16 hs[16], ls[16];
    #pragma unroll
    for (int j = 0; j < 16; ++j) split1(tile[kk0 + j][nn], hs[j], ls[j]);
    size_t ob = (size_t)(bn + nn) * Kp + bk + kk0;
    size_t lo = (size_t)Np * Kp;
    *(short8*)&Wt[ob] = *(short8*)hs;
    *(short8*)&Wt[ob + 8] = *(short8*)&hs[8];
    *(short8*)&Wt[lo + ob] = *(short8*)ls;
    *(short8*)&Wt[lo + ob + 8] = *(short8*)&ls[8];
}

// ---------------- scatter_prep: bucketize + weight splits + stats/zpad zero ----
__global__ __launch_bounds__(256)
void scatter_prep(const int* __restrict__ ei,
                  unsigned* __restrict__ bucketArr, unsigned* __restrict__ cnts,
                  float* __restrict__ stats, float* __restrict__ zpad,
                  const float* __restrict__ W0, const float* __restrict__ fW1,
                  u16* __restrict__ W0t, u16* __restrict__ fW1t) {
    __shared__ char smem[16704];
    __shared__ unsigned cnt[NBUCK];
    int b = blockIdx.x;
    int t = threadIdx.x;
    if (b < 64) {
        if (t < NBUCK) cnt[t] = 0;
        __syncthreads();
        int base = b * EPB;
        #pragma unroll
        for (int k = 0; k < 20; ++k) {
            int el = t + k * 256;
            if (el < EPB) {
                int e = base + el;
                unsigned i = (unsigned)ei[e], j = (unsigned)ei[NE + e];
                unsigned bk = (i / BROWS) * 2 + (j >= HBITS ? 1u : 0u);
                unsigned key = (i << 14) | j;
                unsigned pos = atomicAdd(&cnt[bk], 1u);
                if (pos < SUBCAP)
                    bucketArr[((size_t)bk << 13) + ((unsigned)b << 7) + pos] = key;
            }
        }
        __syncthreads();
        if (t < NBUCK) cnts[(t << 6) + b] = min(cnt[t], (unsigned)SUBCAP);
    } else if (b < 96) {
        int idx = b - 64;
        splitW_dev(W0, 500, 256, 512, 256, W0t, idx & 7, idx >> 3, smem);
    } else {
        int base = (b - 96) * 512;
        stats[base + t] = 0.f;
        stats[base + 256 + t] = 0.f;
        if (b == 96 && t < 64) zpad[t] = 0.f;
        splitW_dev(fW1, 128, 40, 128, 64, fW1t, b - 96, 0, smem);
    }
}

// ---------------- bucket_degree: LDS-bitmap dedup + popcount -> degh -----------
__global__ __launch_bounds__(256)
void bucket_degree(const unsigned* __restrict__ bucketArr,
                   const unsigned* __restrict__ cnts,
                   float* __restrict__ degh) {
    __shared__ unsigned lbm[BROWS * HWORDS];   // 102,400 B
    int b = blockIdx.x, t = threadIdx.x;
    int rr = b >> 1, h = b & 1;
    int row0 = rr * BROWS;
    {
        uint4* z = (uint4*)lbm;
        #pragma unroll
        for (int i = 0; i < 25; ++i) z[t + i * 256] = (uint4){0u, 0u, 0u, 0u};
    }
    __syncthreads();
    for (int r = t; r < BROWS; r += 256) {
        int i = row0 + r;
        if (i < NN && ((i >= HBITS) == (h == 1))) {
            int jj = i - h * HBITS;
            atomicOr(&lbm[r * HWORDS + (jj >> 5)], 1u << (jj & 31));
        }
    }
    {
        int sb = t >> 2, kl = t & 3;
        unsigned n = cnts[(b << 6) + sb];
        const unsigned* keys = bucketArr + ((size_t)b << 13) + ((unsigned)sb << 7);
        for (unsigned k = kl; k < n; k += 4) {
            unsigned key = keys[k];
            unsigned i = key >> 14, j = key & 0x3FFFu;
            unsigned r = i - row0;
            unsigned jj = j - h * HBITS;
            atomicOr(&lbm[r * HWORDS + (jj >> 5)], 1u << (jj & 31));
        }
    }
    __syncthreads();
    #pragma unroll
    for (int pass = 0; pass < 3; ++pass) {
        int r = pass * 64 + (t >> 2), wl = t & 3;
        if (r >= BROWS) break;
        int i = row0 + r;
        int c = 0;
        const uint4* rp = (const uint4*)&lbm[r * HWORDS + wl * 40];
        #pragma unroll
        for (int m = 0; m < 10; ++m) {
            uint4 v = rp[m];
            c += __popc(v.x) + __popc(v.y) + __popc(v.z) + __popc(v.w);
        }
        c += __shfl_down(c, 1, 4);
        c += __shfl_down(c, 2, 4);
        if (wl == 0 && i < MP) degh[h * MP + i] = (float)c;
    }
}

// ================= GEMM phase bodies (bit-identical to verified r6) ============

// conv0: x staged to LDS via gll16 (pre-swizzled source), split in-kernel.
// smem needs 49152 B; sdeg = 64 floats.
__device__ __forceinline__
void conv0_body(int b, const float* __restrict__ x, const float* __restrict__ zpad,
                const u16* __restrict__ Bhi, const u16* __restrict__ Blo,
                const float* __restrict__ degh, const float* __restrict__ bias,
                float* __restrict__ stats,
                u16* __restrict__ Ohi, u16* __restrict__ Olo,
                char* smem, float* sdeg) {
    const int Kp = 512, M = NN, No = 256;
    const int xcd = b & 7, g = b >> 3;
    const int bx = g & 3, by = (g >> 2) * 8 + xcd;
    if (by >= 158) return;   // block-uniform; safe (no syncthreads outside)
    const int t = threadIdx.x;
    const int lane = t & 63;
    const int w = t >> 6;
    const int q = lane >> 4;
    const int l16 = lane & 15;
    const int m7 = l16 & 7;
    const int row0 = by * 64;
    const int col0 = bx * 64;

    const u16* srcs[4];
    unsigned dstoff[4];
    #pragma unroll
    for (int i = 0; i < 4; ++i) {
        int j = w + (i & 1) * 4;
        int plane = i >> 1;
        int r = j * 8 + (lane >> 3);
        int c = (lane & 7) ^ (r & 7);
        srcs[i] = (plane ? Blo : Bhi) + (size_t)(col0 + r) * Kp + c * 8;
        dstoff[i] = 16384 + plane * 8192 + j * 1024;
    }

    int xrow[4];
    int xcol[4];
    unsigned xdst[4];
    #pragma unroll
    for (int i = 0; i < 4; ++i) {
        int slab = w * 4 + i;
        int row = slab * 4 + (lane >> 4);
        int cl = (lane & 15) ^ (row & 15);
        xrow[i] = row0 + row;
        xcol[i] = cl * 4;
        xdst[i] = 32768 + slab * 1024;
    }

    #pragma unroll
    for (int i = 0; i < 4; ++i) gll16(srcs[i], smem + dstoff[i]);
    #pragma unroll
    for (int i = 0; i < 4; ++i) {
        int col = xcol[i];
        const float* s = (xrow[i] < NN && col < 500)
                       ? x + (size_t)xrow[i] * 500 + col : zpad;
        gll16(s, smem + xdst[i]);
    }

    if (t < 64) sdeg[t] = degh[row0 + t] + degh[MP + row0 + t];

    __syncthreads();   // X(0), B(0) resident

    const int rn = t & 63;
    const int c4 = t >> 6;
    const int ch0 = c4 * 2;
    float vals[16];
    #pragma unroll
    for (int m = 0; m < 4; ++m) {
        int phys = (c4 * 4 + m) ^ (rn & 15);
        float4 v = *(const float4*)(smem + 32768 + rn * 256 + phys * 16);
        vals[m * 4 + 0] = v.x; vals[m * 4 + 1] = v.y;
        vals[m * 4 + 2] = v.z; vals[m * 4 + 3] = v.w;
    }

    __syncthreads();   // all X(0) reads done

    #pragma unroll
    for (int i = 0; i < 4; ++i) {
        int col = 64 + xcol[i];
        const float* s = (xrow[i] < NN && col < 500)
                       ? x + (size_t)xrow[i] * 500 + col : zpad;
        gll16(s, smem + xdst[i]);
    }
    #pragma unroll
    for (int i = 0; i < 4; ++i) srcs[i] += 64;

    f32x4 acc[4];
    #pragma unroll
    for (int s = 0; s < 4; ++s) acc[s] = (f32x4){0.f, 0.f, 0.f, 0.f};

    for (int k0 = 0; k0 < Kp; k0 += 64) {
        {
            u16 hs[16], ls[16];
            #pragma unroll
            for (int i2 = 0; i2 < 16; ++i2) split1(vals[i2], hs[i2], ls[i2]);
            unsigned o0 = rn * 128 + ((ch0 ^ (rn & 7)) * 16);
            unsigned o1 = rn * 128 + (((ch0 + 1) ^ (rn & 7)) * 16);
            *(short8*)(smem + o0) = *(short8*)&hs[0];
            *(short8*)(smem + o1) = *(short8*)&hs[8];
            *(short8*)(smem + 8192 + o0) = *(short8*)&ls[0];
            *(short8*)(smem + 8192 + o1) = *(short8*)&ls[8];
        }
        __syncthreads();   // (1)
        short8 ah[2], al[2], bh[2][4], bl[2][4];
        #pragma unroll
        for (int kc = 0; kc < 2; ++kc) {
            int aoff = (w * 16 + l16) * 128 + (((kc * 4 + q) ^ m7) * 16);
            ah[kc] = *(const short8*)(smem + aoff);
            al[kc] = *(const short8*)(smem + 8192 + aoff);
            #pragma unroll
            for (int s = 0; s < 4; ++s) {
                int boff = 16384 + (s * 16 + l16) * 128 + (((kc * 4 + q) ^ m7) * 16);
                bh[kc][s] = *(const short8*)(smem + boff);
                bl[kc][s] = *(const short8*)(smem + 8192 + boff);
            }
        }
        bool more = (k0 + 64 < Kp);
        if (more) {
            #pragma unroll
            for (int m = 0; m < 4; ++m) {
                int phys = (c4 * 4 + m) ^ (rn & 15);
                float4 v = *(const float4*)(smem + 32768 + rn * 256 + phys * 16);
                vals[m * 4 + 0] = v.x; vals[m * 4 + 1] = v.y;
                vals[m * 4 + 2] = v.z; vals[m * 4 + 3] = v.w;
            }
        }
        __syncthreads();   // (2)
        if (more) {
            #pragma unroll
            for (int i = 0; i < 4; ++i) { gll16(srcs[i], smem + dstoff[i]); srcs[i] += 64; }
            if (k0 + 128 < Kp) {
                #pragma unroll
                for (int i = 0; i < 4; ++i) {
                    int col = k0 + 128 + xcol[i];
                    const float* s = (xrow[i] < NN && col < 500)
                                   ? x + (size_t)xrow[i] * 500 + col : zpad;
                    gll16(s, smem + xdst[i]);
                }
            }
        }
        #pragma unroll
        for (int kc = 0; kc < 2; ++kc)
            #pragma unroll
            for (int s = 0; s < 4; ++s) {
                acc[s] = __builtin_amdgcn_mfma_f32_16x16x32_bf16(al[kc], bh[kc][s], acc[s], 0, 0, 0);
                acc[s] = __builtin_amdgcn_mfma_f32_16x16x32_bf16(ah[kc], bl[kc][s], acc[s], 0, 0, 0);
                acc[s] = __builtin_amdgcn_mfma_f32_16x16x32_bf16(ah[kc], bh[kc][s], acc[s], 0, 0, 0);
            }
    }

    int growb = row0 + w * 16 + q * 4;
    float dgv[4];
    #pragma unroll
    for (int r = 0; r < 4; ++r) {
        int grow = growb + r;
        dgv[r] = (grow < M) ? sdeg[grow - row0] : 0.f;
    }
    #pragma unroll
    for (int s = 0; s < 4; ++s) {
        int gc = col0 + s * 16 + l16;
        float bia = bias[gc];
        float s_sum = 0.f, ss_sum = 0.f;
        #pragma unroll
        for (int r = 0; r < 4; ++r) {
            int grow = growb + r;
            bool real = grow < M;
            float v = fmaxf(fmaf(dgv[r], acc[s][r], bia), 0.f);
            if (!real) v = 0.f;
            s_sum += v; ss_sum += v * v;
            float vo = v * dgv[r];
            u16 h, l; split1(vo, h, l);
            Ohi[(size_t)grow * No + gc] = h;
            Olo[(size_t)grow * No + gc] = l;
        }
        s_sum  += __shfl_xor(s_sum, 16);  s_sum  += __shfl_xor(s_sum, 32);
        ss_sum += __shfl_xor(ss_sum, 16); ss_sum += __shfl_xor(ss_sum, 32);
        if (lane < 16) {
            atomicAdd(&stats[gc], s_sum);
            atomicAdd(&stats[256 + gc], ss_sum);
        }
    }
}

// conv1: in-kernel BN0 fold of W1. smem needs 32768 B; saux = 832 floats.
__device__ __forceinline__
void conv1_body(int b, const u16* __restrict__ Ahi, const u16* __restrict__ Alo,
                const float* __restrict__ W1, const float* __restrict__ stats0,
                const float* __restrict__ g0, const float* __restrict__ bb0,
                const float* __restrict__ b1, const float* __restrict__ degh,
                float* __restrict__ stats1, u16* __restrict__ Ohi, u16* __restrict__ Olo,
                char* smem, float* saux) {
    float* scl = saux;
    float* sh = saux + 256;
    float* cred = saux + 512;
    float* cvec = saux + 768;
    const int Kp = 256, M = NN, No = 256;
    const int xcd = b & 7, g = b >> 3;
    const int bx = g & 3, by = (g >> 2) * 8 + xcd;
    if (by >= 158) return;
    const int t = threadIdx.x;
    const int lane = t & 63;
    const int w = t >> 6;
    const int q = lane >> 4;
    const int l16 = lane & 15;
    const int m7 = l16 & 7;
    const int row0 = by * 64;
    const int col0 = bx * 64;

    const u16* srcs[4];
    unsigned dstoff[4];
    #pragma unroll
    for (int i = 0; i < 4; ++i) {
        int gi = w + i * 4;
        int plane = gi >> 3, j = gi & 7;
        int r = j * 8 + (lane >> 3);
        int c = (lane & 7) ^ (r & 7);
        srcs[i] = (plane ? Alo : Ahi) + (size_t)(row0 + r) * Kp + c * 8;
        dstoff[i] = plane * 8192 + j * 1024;
    }
    #pragma unroll
    for (int i = 0; i < 4; ++i) { gll16(srcs[i], smem + dstoff[i]); srcs[i] += 64; }

    {
        float mean = stats0[t] * (1.f / NN);
        float var = stats0[256 + t] * (1.f / NN) - mean * mean;
        float s = g0[t] * rsqrtf(var + BN_EPS);
        scl[t] = s;
        sh[t] = bb0[t] - mean * s;
    }
    __syncthreads();
    {
        float s = 0.f;
        int n = col0 + (t & 63);
        #pragma unroll 8
        for (int k = (t >> 6); k < 256; k += 4)
            s += sh[k] * W1[(size_t)k * 256 + n];
        cred[t] = s;
        __syncthreads();
        if (t < 64) cvec[t] = cred[t] + cred[t + 64] + cred[t + 128] + cred[t + 192];
    }
    const int bn = t & 63;
    const int kb = (t >> 6) * 16;
    const int ch0 = (t >> 6) * 2;
    float vals[16];
    {
        const float* wp = W1 + (size_t)kb * 256 + col0 + bn;
        #pragma unroll
        for (int i = 0; i < 16; ++i) vals[i] = wp[(size_t)i * 256] * scl[kb + i];
    }

    f32x4 acc[4];
    #pragma unroll
    for (int s = 0; s < 4; ++s) acc[s] = (f32x4){0.f, 0.f, 0.f, 0.f};

    for (int k0 = 0; k0 < Kp; k0 += 64) {
        {
            u16 hs[16], ls[16];
            #pragma unroll
            for (int i = 0; i < 16; ++i) split1(vals[i], hs[i], ls[i]);
            unsigned o0 = bn * 128 + ((ch0 ^ (bn & 7)) * 16);
            unsigned o1 = bn * 128 + (((ch0 + 1) ^ (bn & 7)) * 16);
            *(short8*)(smem + 16384 + o0) = *(short8*)&hs[0];
            *(short8*)(smem + 16384 + o1) = *(short8*)&hs[8];
            *(short8*)(smem + 24576 + o0) = *(short8*)&ls[0];
            *(short8*)(smem + 24576 + o1) = *(short8*)&ls[8];
        }
        __syncthreads();   // (1)
        short8 ah[2], al[2], bh[2][4], bl[2][4];
        #pragma unroll
        for (int kc = 0; kc < 2; ++kc) {
            int aoff = (w * 16 + l16) * 128 + (((kc * 4 + q) ^ m7) * 16);
            ah[kc] = *(const short8*)(smem + aoff);
            al[kc] = *(const short8*)(smem + 8192 + aoff);
            #pragma unroll
            for (int s = 0; s < 4; ++s) {
                int boff = (s * 16 + l16) * 128 + (((kc * 4 + q) ^ m7) * 16);
                bh[kc][s] = *(const short8*)(smem + 16384 + boff);
                bl[kc][s] = *(const short8*)(smem + 24576 + boff);
            }
        }
        __syncthreads();   // (2)
        if (k0 + 64 < Kp) {
            #pragma unroll
            for (int i = 0; i < 4; ++i) { gll16(srcs[i], smem + dstoff[i]); srcs[i] += 64; }
            const float* wp = W1 + (size_t)(k0 + 64 + kb) * 256 + col0 + bn;
            #pragma unroll
            for (int i = 0; i < 16; ++i) vals[i] = wp[(size_t)i * 256] * scl[k0 + 64 + kb + i];
        }
        #pragma unroll
        for (int kc = 0; kc < 2; ++kc)
            #pragma unroll
            for (int s = 0; s < 4; ++s) {
                acc[s] = __builtin_amdgcn_mfma_f32_16x16x32_bf16(al[kc], bh[kc][s], acc[s], 0, 0, 0);
                acc[s] = __builtin_amdgcn_mfma_f32_16x16x32_bf16(ah[kc], bl[kc][s], acc[s], 0, 0, 0);
                acc[s] = __builtin_amdgcn_mfma_f32_16x16x32_bf16(ah[kc], bh[kc][s], acc[s], 0, 0, 0);
            }
    }

    int growb = row0 + w * 16 + q * 4;
    float dgv[4];
    #pragma unroll
    for (int r = 0; r < 4; ++r) {
        int grow = growb + r;
        dgv[r] = (grow < M) ? (degh[grow] + degh[MP + grow]) : 0.f;
    }
    #pragma unroll
    for (int s = 0; s < 4; ++s) {
        int gc = col0 + s * 16 + l16;
        float bia = b1[gc];
        float cv = cvec[s * 16 + l16];
        float s_sum = 0.f, ss_sum = 0.f;
        #pragma unroll
        for (int r = 0; r < 4; ++r) {
            int grow = growb + r;
            bool real = grow < M;
            float v = fmaxf(fmaf(dgv[r], cv, acc[s][r] + bia), 0.f);
            if (!real) v = 0.f;
            s_sum += v; ss_sum += v * v;
            u16 h, l; split1(v, h, l);
            Ohi[(size_t)grow * No + gc] = h;
            Olo[(size_t)grow * No + gc] = l;
        }
        s_sum  += __shfl_xor(s_sum, 16);  s_sum  += __shfl_xor(s_sum, 32);
        ss_sum += __shfl_xor(ss_sum, 16); ss_sum += __shfl_xor(ss_sum, 32);
        if (lane < 16) {
            atomicAdd(&stats1[gc], s_sum);
            atomicAdd(&stats1[256 + gc], ss_sum);
        }
    }
}

// fc0: in-kernel BN1 fold of fW0. smem needs 32768 B; saux = 832 floats.
__device__ __forceinline__
void fc0_body(int b, const u16* __restrict__ Ahi, const u16* __restrict__ Alo,
              const float* __restrict__ fW0, const float* __restrict__ stats1,
              const float* __restrict__ g1, const float* __restrict__ bb1,
              const float* __restrict__ fb0,
              u16* __restrict__ Ohi, u16* __restrict__ Olo,
              char* smem, float* saux) {
    float* scl = saux;
    float* sh = saux + 256;
    float* cred = saux + 512;
    float* biasf = saux + 768;
    const int Kp = 256, M = NN, No = 128;
    const int xcd = b & 7, g = b >> 3;
    const int bx = g & 1, by = (g >> 1) * 8 + xcd;
    if (by >= 158) return;
    const int t = threadIdx.x;
    const int lane = t & 63;
    const int w = t >> 6;
    const int q = lane >> 4;
    const int l16 = lane & 15;
    const int m7 = l16 & 7;
    const int row0 = by * 64;
    const int col0 = bx * 64;

    const u16* srcs[4];
    unsigned dstoff[4];
    #pragma unroll
    for (int i = 0; i < 4; ++i) {
        int gi = w + i * 4;
        int plane = gi >> 3, j = gi & 7;
        int r = j * 8 + (lane >> 3);
        int c = (lane & 7) ^ (r & 7);
        srcs[i] = (plane ? Alo : Ahi) + (size_t)(row0 + r) * Kp + c * 8;
        dstoff[i] = plane * 8192 + j * 1024;
    }
    #pragma unroll
    for (int i = 0; i < 4; ++i) { gll16(srcs[i], smem + dstoff[i]); srcs[i] += 64; }

    {
        float mean = stats1[t] * (1.f / NN);
        float var = stats1[256 + t] * (1.f / NN) - mean * mean;
        float s = g1[t] * rsqrtf(var + BN_EPS);
        scl[t] = s;
        sh[t] = bb1[t] - mean * s;
    }
    __syncthreads();
    {
        float s = 0.f;
        int n = col0 + (t & 63);
        #pragma unroll 8
        for (int k = (t >> 6); k < 256; k += 4)
            s += sh[k] * fW0[(size_t)k * 128 + n];
        cred[t] = s;
        __syncthreads();
        if (t < 64)
            biasf[t] = fb0[col0 + t] + cred[t] + cred[t + 64] + cred[t + 128] + cred[t + 192];
    }
    const int bn = t & 63;
    const int kb = (t >> 6) * 16;
    const int ch0 = (t >> 6) * 2;
    float vals[16];
    {
        const float* wp = fW0 + (size_t)kb * 128 + col0 + bn;
        #pragma unroll
        for (int i = 0; i < 16; ++i) vals[i] = wp[(size_t)i * 128] * scl[kb + i];
    }

    f32x4 acc[4];
    #pragma unroll
    for (int s = 0; s < 4; ++s) acc[s] = (f32x4){0.f, 0.f, 0.f, 0.f};

    for (int k0 = 0; k0 < Kp; k0 += 64) {
        {
            u16 hs[16], ls[16];
            #pragma unroll
            for (int i = 0; i < 16; ++i) split1(vals[i], hs[i], ls[i]);
            unsigned o0 = bn * 128 + ((ch0 ^ (bn & 7)) * 16);
            unsigned o1 = bn * 128 + (((ch0 + 1) ^ (bn & 7)) * 16);
            *(short8*)(smem + 16384 + o0) = *(short8*)&hs[0];
            *(short8*)(smem + 16384 + o1) = *(short8*)&hs[8];
            *(short8*)(smem + 24576 + o0) = *(short8*)&ls[0];
            *(short8*)(smem + 24576 + o1) = *(short8*)&ls[8];
        }
        __syncthreads();   // (1)
        short8 ah[2], al[2], bh[2][4], bl[2][4];
        #pragma unroll
        for (int kc = 0; kc < 2; ++kc) {
            int aoff = (w * 16 + l16) * 128 + (((kc * 4 + q) ^ m7) * 16);
            ah[kc] = *(const short8*)(smem + aoff);
            al[kc] = *(const short8*)(smem + 8192 + aoff);
            #pragma unroll
            for (int s = 0; s < 4; ++s) {
                int boff = (s * 16 + l16) * 128 + (((kc * 4 + q) ^ m7) * 16);
                bh[kc][s] = *(const short8*)(smem + 16384 + boff);
                bl[kc][s] = *(const short8*)(smem + 24576 + boff);
            }
        }
        __syncthreads();   // (2)
        if (k0 + 64 < Kp) {
            #pragma unroll
            for (int i = 0; i < 4; ++i) { gll16(srcs[i], smem + dstoff[i]); srcs[i] += 64; }
            const float* wp = fW0 + (size_t)(k0 + 64 + kb) * 128 + col0 + bn;
            #pragma unroll
            for (int i = 0; i < 16; ++i) vals[i] = wp[(size_t)i * 128] * scl[k0 + 64 + kb + i];
        }
        #pragma unroll
        for (int kc = 0; kc < 2; ++kc)
            #pragma unroll
            for (int s = 0; s < 4; ++s) {
                acc[s] = __builtin_amdgcn_mfma_f32_16x16x32_bf16(al[kc], bh[kc][s], acc[s], 0, 0, 0);
                acc[s] = __builtin_amdgcn_mfma_f32_16x16x32_bf16(ah[kc], bl[kc][s], acc[s], 0, 0, 0);
                acc[s] = __builtin_amdgcn_mfma_f32_16x16x32_bf16(ah[kc], bh[kc][s], acc[s], 0, 0, 0);
            }
    }

    int growb = row0 + w * 16 + q * 4;
    #pragma unroll
    for (int s = 0; s < 4; ++s) {
        int gc = col0 + s * 16 + l16;
        float bia = biasf[s * 16 + l16];
        #pragma unroll
        for (int r = 0; r < 4; ++r) {
            int grow = growb + r;
            float v = fmaxf(acc[s][r] + bia, 0.f);
            if (grow >= M) v = 0.f;
            u16 h, l; split1(v, h, l);
            Ohi[(size_t)grow * No + gc] = h;
            Olo[(size_t)grow * No + gc] = l;
        }
    }
}

// fc1: Kp=128, N=40, fp32 out. smem needs 32768 B.
__device__ __forceinline__
void fc1_body(int b, const u16* __restrict__ Ahi, const u16* __restrict__ Alo,
              const u16* __restrict__ Bhi, const u16* __restrict__ Blo,
              const float* __restrict__ bias, float* __restrict__ out, char* smem) {
    const int Kp = 128, M = NN, N = 40, No = 40;
    const int t = threadIdx.x;
    const int lane = t & 63;
    const int w = t >> 6;
    const int q = lane >> 4;
    const int l16 = lane & 15;
    const int m7 = l16 & 7;
    const int row0 = b * 64;
    const int col0 = 0;

    const u16* bases[4] = {Ahi, Alo, Bhi, Blo};
    const u16* srcs[8];
    unsigned dstoff[8];
    #pragma unroll
    for (int i = 0; i < 8; ++i) {
        int gi = w + i * 4;
        int reg = i >> 1;
        int j = gi & 7;
        int rb = (reg < 2) ? row0 : col0;
        int r = j * 8 + (lane >> 3);
        int c = (lane & 7) ^ (r & 7);
        srcs[i] = bases[reg] + (size_t)(rb + r) * Kp + c * 8;
        dstoff[i] = reg * 8192 + j * 1024;
    }

    f32x4 acc[4];
    #pragma unroll
    for (int s = 0; s < 4; ++s) acc[s] = (f32x4){0.f, 0.f, 0.f, 0.f};

    #pragma unroll
    for (int i = 0; i < 8; ++i) { gll16(srcs[i], smem + dstoff[i]); srcs[i] += 64; }

    for (int k0 = 0; k0 < Kp; k0 += 64) {
        __syncthreads();
        short8 ah[2], al[2], bh[2][4], bl[2][4];
        #pragma unroll
        for (int kc = 0; kc < 2; ++kc) {
            int aoff = (w * 16 + l16) * 128 + (((kc * 4 + q) ^ m7) * 16);
            ah[kc] = *(const short8*)(smem + aoff);
            al[kc] = *(const short8*)(smem + 8192 + aoff);
            #pragma unroll
            for (int s = 0; s < 4; ++s) {
                int boff = (s * 16 + l16) * 128 + (((kc * 4 + q) ^ m7) * 16);
                bh[kc][s] = *(const short8*)(smem + 16384 + boff);
                bl[kc][s] = *(const short8*)(smem + 24576 + boff);
            }
        }
        __syncthreads();
        if (k0 + 64 < Kp) {
            #pragma unroll
            for (int i = 0; i < 8; ++i) { gll16(srcs[i], smem + dstoff[i]); srcs[i] += 64; }
        }
        #pragma unroll
        for (int kc = 0; kc < 2; ++kc)
            #pragma unroll
            for (int s = 0; s < 4; ++s) {
                acc[s] = __builtin_amdgcn_mfma_f32_16x16x32_bf16(al[kc], bh[kc][s], acc[s], 0, 0, 0);
                acc[s] = __builtin_amdgcn_mfma_f32_16x16x32_bf16(ah[kc], bl[kc][s], acc[s], 0, 0, 0);
                acc[s] = __builtin_amdgcn_mfma_f32_16x16x32_bf16(ah[kc], bh[kc][s], acc[s], 0, 0, 0);
            }
    }

    int growb = row0 + w * 16 + q * 4;
    #pragma unroll
    for (int s = 0; s < 4; ++s) {
        int gc = col0 + s * 16 + l16;
        if (gc >= N) continue;
        float bia = bias[gc];
        #pragma unroll
        for (int r = 0; r < 4; ++r) {
            int grow = growb + r;
            if (grow < M)
                out[(size_t)grow * No + gc] = fmaxf(acc[s][r] + bia, 0.f);
        }
    }
}

// ================= standalone kernels (fallback path, proven r6) ===============

__global__ __launch_bounds__(256, 3)
void conv0_gemm(const float* __restrict__ x, const float* __restrict__ zpad,
                const u16* __restrict__ Bhi, const u16* __restrict__ Blo,
                const float* __restrict__ degh, const float* __restrict__ bias,
                float* __restrict__ stats,
                u16* __restrict__ Ohi, u16* __restrict__ Olo) {
    __shared__ char smem[49152];
    __shared__ float saux[64];
    conv0_body(blockIdx.x, x, zpad, Bhi, Blo, degh, bias, stats, Ohi, Olo, smem, saux);
}

__global__ __launch_bounds__(256, 4)
void conv1_fold(const u16* __restrict__ Ahi, const u16* __restrict__ Alo,
                const float* __restrict__ W1, const float* __restrict__ stats0,
                const float* __restrict__ g0, const float* __restrict__ bb0,
                const float* __restrict__ b1, const float* __restrict__ degh,
                float* __restrict__ stats1, u16* __restrict__ Ohi, u16* __restrict__ Olo) {
    __shared__ char smem[32768];
    __shared__ float saux[832];
    conv1_body(blockIdx.x, Ahi, Alo, W1, stats0, g0, bb0, b1, degh, stats1, Ohi, Olo, smem, saux);
}

__global__ __launch_bounds__(256, 4)
void fc0_fold(const u16* __restrict__ Ahi, const u16* __restrict__ Alo,
              const float* __restrict__ fW0, const float* __restrict__ stats1,
              const float* __restrict__ g1, const float* __restrict__ bb1,
              const float* __restrict__ fb0,
              u16* __restrict__ Ohi, u16* __restrict__ Olo) {
    __shared__ char smem[32768];
    __shared__ float saux[832];
    fc0_body(blockIdx.x, Ahi, Alo, fW0, stats1, g1, bb1, fb0, Ohi, Olo, smem, saux);
}

__global__ __launch_bounds__(256, 3)
void fc1_gemm(const u16* __restrict__ Ahi, const u16* __restrict__ Alo,
              const u16* __restrict__ Bhi, const u16* __restrict__ Blo,
              const float* __restrict__ bias, float* __restrict__ out) {
    __shared__ char smem[32768];
    fc1_body(blockIdx.x, Ahi, Alo, Bhi, Blo, bias, out, smem);
}

// ================= cooperative mega-kernel (conv0->conv1->fc0->fc1) ============
// Grid 640x256, 3 blocks/CU (LDS 52.5 KB) -> all co-resident (<=768).
// grid.sync() provides the agent-scope release/acquire needed for cross-XCD
// visibility of H1/H2/H3 plain stores; stats are device-scope atomics.
__global__ __launch_bounds__(256, 3)
void mega_gemm(const float* x, const float* zpad, const u16* Bhi, const u16* Blo,
               const float* degh, const float* b0, float* stats, u16* H1hi, u16* H1lo,
               const float* W1, const float* g0, const float* bb0, const float* b1,
               float* stats1, u16* H2hi, u16* H2lo,
               const float* fW0, const float* g1, const float* bb1, const float* fb0,
               u16* H3hi, u16* H3lo,
               const u16* fBhi, const u16* fBlo, const float* fb1, float* out) {
    __shared__ char smem[49152];
    __shared__ float saux[832];
    cooperative_groups::grid_group grid = cooperative_groups::this_grid();
    const int b = blockIdx.x;

    conv0_body(b, x, zpad, Bhi, Blo, degh, b0, stats, H1hi, H1lo, smem, saux);
    grid.sync();
    conv1_body(b, H1hi, H1lo, W1, stats, g0, bb0, b1, degh, stats1, H2hi, H2lo, smem, saux);
    grid.sync();
    if (b < 320)
        fc0_body(b, H2hi, H2lo, fW0, stats1, g1, bb1, fb0, H3hi, H3lo, smem, saux);
    grid.sync();
    if (b < 158)
        fc1_body(b, H3hi, H3lo, fBhi, fBlo, fb1, out, smem);
}

// ---------------- launch ----------------

extern "C" void kernel_launch(void* const* d_in, const int* in_sizes, int n_in,
                              void* d_out, int out_size, void* d_ws, size_t ws_size,
                              hipStream_t stream) {
    const float* x   = (const float*)d_in[0];
    const int*   ei  = (const int*)d_in[1];
    const float* W0  = (const float*)d_in[2];
    const float* b0  = (const float*)d_in[3];
    const float* g0  = (const float*)d_in[4];
    const float* bb0 = (const float*)d_in[5];
    const float* W1  = (const float*)d_in[6];
    const float* b1  = (const float*)d_in[7];
    const float* g1  = (const float*)d_in[8];
    const float* bb1 = (const float*)d_in[9];
    const float* fW0 = (const float*)d_in[10];
    const float* fb0 = (const float*)d_in[11];
    const float* fW1 = (const float*)d_in[12];
    const float* fb1 = (const float*)d_in[13];
    float* out = (float*)d_out;

    char* ws = (char*)d_ws;
    auto carve = [&](size_t bytes) { char* q = ws; ws += (bytes + 255) & ~(size_t)255; return q; };

    float* stats = (float*)carve(4096);        // zeroed by scatter_prep blocks 96/97
    float* zpad  = (float*)carve(1024);        // zeroed by scatter_prep block 96
    unsigned* cnts = (unsigned*)carve((size_t)NBUCK * 64 * 4);          // fully written
    float* degh = (float*)carve((size_t)2 * MP * 4);                    // fully written
    unsigned* bucketArr = (unsigned*)carve((size_t)NBUCK * 64 * SUBCAP * 4);  // 4 MB
    u16* W0t    = (u16*)carve((size_t)2 * 256 * 512 * 2);
    u16* fW1t   = (u16*)carve((size_t)2 * 64 * 128 * 2);
    u16* H1     = (u16*)carve((size_t)2 * MP * 256 * 2);
    u16* H2     = (u16*)carve((size_t)2 * MP * 256 * 2);
    u16* H3     = (u16*)carve((size_t)2 * MP * 128 * 2);

    dim3 blk(256);

    // 1. bucketize edges + split W0/fW1 + zero stats/zpad
    scatter_prep<<<98, blk, 0, stream>>>(ei, bucketArr, cnts, stats, zpad, W0, fW1, W0t, fW1t);
    // 2. LDS-bitmap dedup + popcount -> degh
    bucket_degree<<<NBUCK, blk, 0, stream>>>(bucketArr, cnts, degh);

    // 3. GEMM chain: one cooperative dispatch (3 boundaries eliminated),
    //    with fallback to the 4 proven separate dispatches.
    {
        const u16* Bhi = W0t;
        const u16* Blo = W0t + 256 * 512;
        u16* H1hi = H1; u16* H1lo = H1 + (size_t)MP * 256;
        u16* H2hi = H2; u16* H2lo = H2 + (size_t)MP * 256;
        u16* H3hi = H3; u16* H3lo = H3 + (size_t)MP * 128;
        const u16* fBhi = fW1t;
        const u16* fBlo = fW1t + 64 * 128;
        float* stats1 = stats + 512;

        void* args[] = {
            (void*)&x, (void*)&zpad, (void*)&Bhi, (void*)&Blo, (void*)&degh,
            (void*)&b0, (void*)&stats, (void*)&H1hi, (void*)&H1lo,
            (void*)&W1, (void*)&g0, (void*)&bb0, (void*)&b1, (void*)&stats1,
            (void*)&H2hi, (void*)&H2lo,
            (void*)&fW0, (void*)&g1, (void*)&bb1, (void*)&fb0,
            (void*)&H3hi, (void*)&H3lo,
            (void*)&fBhi, (void*)&fBlo, (void*)&fb1, (void*)&out};

        hipError_t err = hipLaunchCooperativeKernel(mega_gemm, dim3(640), blk,
                                                    args, 0u, stream);
        if (err != hipSuccess) {
            (void)hipGetLastError();   // clear sticky error; use proven path
            conv0_gemm<<<640, blk, 0, stream>>>(
                x, zpad, Bhi, Blo, degh, b0, stats, H1hi, H1lo);
            conv1_fold<<<640, blk, 0, stream>>>(
                H1hi, H1lo, W1, stats, g0, bb0, b1, degh, stats1, H2hi, H2lo);
            fc0_fold<<<320, blk, 0, stream>>>(
                H2hi, H2lo, fW0, stats1, g1, bb1, fb0, H3hi, H3lo);
            fc1_gemm<<<158, blk, 0, stream>>>(
                H3hi, H3lo, fBhi, fBlo, fb1, out);
        }
    }
}

// Round 8
// 181.480 us; speedup vs baseline: 2.4016x; 2.4016x over previous
//
#include <hip/hip_runtime.h>

#define NN 10000
#define NE 320000
#define MP 10112        // 158*64 padded rows
#define BN_EPS 1e-5f

#define NRANGE 64       // row-ranges (160 rows each)
#define BROWS 160
#define NBUCK 128       // row-range x j-half buckets
#define HBITS 5120      // bits per j-half
#define HWORDS 160      // words per j-half row
#define SUBCAP 128      // keys per (bucket, block) sub-chunk (mean ~39)
#define EPB   5000      // edges per bucketize block (64*5000 = NE exact)

typedef __attribute__((ext_vector_type(8))) short short8;
typedef __attribute__((ext_vector_type(4))) float f32x4;
typedef unsigned short u16;

// ---------------- helpers ----------------
__device__ __forceinline__ void split1(float v, u16& h, u16& l) {
    unsigned int u = __float_as_uint(v);
    h = (u16)(u >> 16);
    float hf = __uint_as_float(u & 0xFFFF0000u);
    l = (u16)(__float_as_uint(v - hf) >> 16);
}

__device__ __forceinline__ void gll16(const void* g, void* l) {
    __builtin_amdgcn_global_load_lds(
        (const __attribute__((address_space(1))) unsigned int*)g,
        (__attribute__((address_space(3))) unsigned int*)l, 16, 0, 0);
}

// ---------------- splitW (proven): Wt[n][k] = split(W[k][n]) ----------------
__device__ void splitW_dev(const float* __restrict__ W, int K, int N, int Kp, int Np,
                           u16* __restrict__ Wt, int bx, int by, char* smem) {
    float (*tile)[65] = (float(*)[65])smem;
    int t = threadIdx.x;
    int bk = bx * 64, bn = by * 64;
    #pragma unroll
    for (int p = 0; p < 4; ++p) {
        int kk = (t >> 4) + p * 16;
        int nc = (t & 15) * 4;
        int k = bk + kk;
        float4 v = {0.f, 0.f, 0.f, 0.f};
        if (k < K && bn + nc + 3 < N)
            v = *(const float4*)&W[(size_t)k * N + bn + nc];
        tile[kk][nc] = v.x; tile[kk][nc + 1] = v.y;
        tile[kk][nc + 2] = v.z; tile[kk][nc + 3] = v.w;
    }
    __syncthreads();
    int nn = t >> 2;
    int kk0 = (t & 3) * 16;
    u16 hs[16], ls[16];
    #pragma unroll
    for (int j = 0; j < 16; ++j) split1(tile[kk0 + j][nn], hs[j], ls[j]);
    size_t ob = (size_t)(bn + nn) * Kp + bk + kk0;
    size_t lo = (size_t)Np * Kp;
    *(short8*)&Wt[ob] = *(short8*)hs;
    *(short8*)&Wt[ob + 8] = *(short8*)&hs[8];
    *(short8*)&Wt[lo + ob] = *(short8*)ls;
    *(short8*)&Wt[lo + ob + 8] = *(short8*)&ls[8];
}

// ---------------- edge_bucketize: the ONLY producer degree_prep waits on -------
__global__ __launch_bounds__(256)
void edge_bucketize(const int* __restrict__ ei,
                    unsigned* __restrict__ bucketArr, unsigned* __restrict__ cnts) {
    __shared__ unsigned cnt[NBUCK];
    int b = blockIdx.x;
    int t = threadIdx.x;
    if (t < NBUCK) cnt[t] = 0;
    __syncthreads();
    int base = b * EPB;
    #pragma unroll
    for (int k = 0; k < 20; ++k) {
        int el = t + k * 256;
        if (el < EPB) {
            int e = base + el;
            unsigned i = (unsigned)ei[e], j = (unsigned)ei[NE + e];
            unsigned bk = (i / BROWS) * 2 + (j >= HBITS ? 1u : 0u);
            unsigned key = (i << 14) | j;
            unsigned pos = atomicAdd(&cnt[bk], 1u);
            if (pos < SUBCAP)
                bucketArr[((size_t)bk << 13) + ((unsigned)b << 7) + pos] = key;
        }
    }
    __syncthreads();
    if (t < NBUCK) cnts[(t << 6) + b] = min(cnt[t], (unsigned)SUBCAP);
}

// ---------------- degree_prep: LDS-bitmap dedup ∥ weight splits ∥ stats zero ---
// [0,128): degree (one block = 160-row range x one j-half, 100 KB LDS bitmap);
// [128,160): W0 split; [160,162): fW1 split + stats/zpad zero.
__global__ __launch_bounds__(256)
void degree_prep(const unsigned* __restrict__ bucketArr,
                 const unsigned* __restrict__ cnts,
                 float* __restrict__ degh,
                 float* __restrict__ stats, float* __restrict__ zpad,
                 const float* __restrict__ W0, const float* __restrict__ fW1,
                 u16* __restrict__ W0t, u16* __restrict__ fW1t) {
    __shared__ char smem[102400];
    int b = blockIdx.x, t = threadIdx.x;
    if (b < NBUCK) {
        unsigned* lbm = (unsigned*)smem;
        int rr = b >> 1, h = b & 1;
        int row0 = rr * BROWS;
        {
            uint4* z = (uint4*)lbm;
            #pragma unroll
            for (int i = 0; i < 25; ++i) z[t + i * 256] = (uint4){0u, 0u, 0u, 0u};
        }
        __syncthreads();
        for (int r = t; r < BROWS; r += 256) {
            int i = row0 + r;
            if (i < NN && ((i >= HBITS) == (h == 1))) {
                int jj = i - h * HBITS;
                atomicOr(&lbm[r * HWORDS + (jj >> 5)], 1u << (jj & 31));
            }
        }
        {
            int sb = t >> 2, kl = t & 3;
            unsigned n = cnts[(b << 6) + sb];
            const unsigned* keys = bucketArr + ((size_t)b << 13) + ((unsigned)sb << 7);
            for (unsigned k = kl; k < n; k += 4) {
                unsigned key = keys[k];
                unsigned i = key >> 14, j = key & 0x3FFFu;
                unsigned r = i - row0;
                unsigned jj = j - h * HBITS;
                atomicOr(&lbm[r * HWORDS + (jj >> 5)], 1u << (jj & 31));
            }
        }
        __syncthreads();
        #pragma unroll
        for (int pass = 0; pass < 3; ++pass) {
            int r = pass * 64 + (t >> 2), wl = t & 3;
            if (r >= BROWS) break;
            int i = row0 + r;
            int c = 0;
            const uint4* rp = (const uint4*)&lbm[r * HWORDS + wl * 40];
            #pragma unroll
            for (int m = 0; m < 10; ++m) {
                uint4 v = rp[m];
                c += __popc(v.x) + __popc(v.y) + __popc(v.z) + __popc(v.w);
            }
            c += __shfl_down(c, 1, 4);
            c += __shfl_down(c, 2, 4);
            if (wl == 0 && i < MP) degh[h * MP + i] = (float)c;
        }
    } else if (b < 160) {
        int idx = b - 128;
        splitW_dev(W0, 500, 256, 512, 256, W0t, idx & 7, idx >> 3, smem);
    } else {
        int base = (b - 160) * 512;
        stats[base + t] = 0.f;
        stats[base + 256 + t] = 0.f;
        if (b == 160 && t < 64) zpad[t] = 0.f;
        splitW_dev(fW1, 128, 40, 128, 64, fW1t, b - 160, 0, smem);
    }
}

// ---------------- conv0 GEMM (verified r6): x staged to LDS via gll16 ----------
__global__ __launch_bounds__(256, 3)
void conv0_gemm(const float* __restrict__ x, const float* __restrict__ zpad,
                const u16* __restrict__ Bhi, const u16* __restrict__ Blo,
                const float* __restrict__ degh, const float* __restrict__ bias,
                float* __restrict__ stats,
                u16* __restrict__ Ohi, u16* __restrict__ Olo) {
    __shared__ char smem[49152];
    __shared__ float sdeg[64];
    const int Kp = 512, M = NN, No = 256;
    const int b = blockIdx.x;
    const int xcd = b & 7, g = b >> 3;
    const int bx = g & 3, by = (g >> 2) * 8 + xcd;
    if (by >= 158) return;
    const int t = threadIdx.x;
    const int lane = t & 63;
    const int w = t >> 6;
    const int q = lane >> 4;
    const int l16 = lane & 15;
    const int m7 = l16 & 7;
    const int row0 = by * 64;
    const int col0 = bx * 64;

    const u16* srcs[4];
    unsigned dstoff[4];
    #pragma unroll
    for (int i = 0; i < 4; ++i) {
        int j = w + (i & 1) * 4;
        int plane = i >> 1;
        int r = j * 8 + (lane >> 3);
        int c = (lane & 7) ^ (r & 7);
        srcs[i] = (plane ? Blo : Bhi) + (size_t)(col0 + r) * Kp + c * 8;
        dstoff[i] = 16384 + plane * 8192 + j * 1024;
    }

    int xrow[4];
    int xcol[4];
    unsigned xdst[4];
    #pragma unroll
    for (int i = 0; i < 4; ++i) {
        int slab = w * 4 + i;
        int row = slab * 4 + (lane >> 4);
        int cl = (lane & 15) ^ (row & 15);
        xrow[i] = row0 + row;
        xcol[i] = cl * 4;
        xdst[i] = 32768 + slab * 1024;
    }

    #pragma unroll
    for (int i = 0; i < 4; ++i) gll16(srcs[i], smem + dstoff[i]);
    #pragma unroll
    for (int i = 0; i < 4; ++i) {
        int col = xcol[i];
        const float* s = (xrow[i] < NN && col < 500)
                       ? x + (size_t)xrow[i] * 500 + col : zpad;
        gll16(s, smem + xdst[i]);
    }

    if (t < 64) sdeg[t] = degh[row0 + t] + degh[MP + row0 + t];

    __syncthreads();   // X(0), B(0) resident

    const int rn = t & 63;
    const int c4 = t >> 6;
    const int ch0 = c4 * 2;
    float vals[16];
    #pragma unroll
    for (int m = 0; m < 4; ++m) {
        int phys = (c4 * 4 + m) ^ (rn & 15);
        float4 v = *(const float4*)(smem + 32768 + rn * 256 + phys * 16);
        vals[m * 4 + 0] = v.x; vals[m * 4 + 1] = v.y;
        vals[m * 4 + 2] = v.z; vals[m * 4 + 3] = v.w;
    }

    __syncthreads();   // all X(0) reads done

    #pragma unroll
    for (int i = 0; i < 4; ++i) {
        int col = 64 + xcol[i];
        const float* s = (xrow[i] < NN && col < 500)
                       ? x + (size_t)xrow[i] * 500 + col : zpad;
        gll16(s, smem + xdst[i]);
    }
    #pragma unroll
    for (int i = 0; i < 4; ++i) srcs[i] += 64;

    f32x4 acc[4];
    #pragma unroll
    for (int s = 0; s < 4; ++s) acc[s] = (f32x4){0.f, 0.f, 0.f, 0.f};

    for (int k0 = 0; k0 < Kp; k0 += 64) {
        {
            u16 hs[16], ls[16];
            #pragma unroll
            for (int i2 = 0; i2 < 16; ++i2) split1(vals[i2], hs[i2], ls[i2]);
            unsigned o0 = rn * 128 + ((ch0 ^ (rn & 7)) * 16);
            unsigned o1 = rn * 128 + (((ch0 + 1) ^ (rn & 7)) * 16);
            *(short8*)(smem + o0) = *(short8*)&hs[0];
            *(short8*)(smem + o1) = *(short8*)&hs[8];
            *(short8*)(smem + 8192 + o0) = *(short8*)&ls[0];
            *(short8*)(smem + 8192 + o1) = *(short8*)&ls[8];
        }
        __syncthreads();   // (1)
        short8 ah[2], al[2], bh[2][4], bl[2][4];
        #pragma unroll
        for (int kc = 0; kc < 2; ++kc) {
            int aoff = (w * 16 + l16) * 128 + (((kc * 4 + q) ^ m7) * 16);
            ah[kc] = *(const short8*)(smem + aoff);
            al[kc] = *(const short8*)(smem + 8192 + aoff);
            #pragma unroll
            for (int s = 0; s < 4; ++s) {
                int boff = 16384 + (s * 16 + l16) * 128 + (((kc * 4 + q) ^ m7) * 16);
                bh[kc][s] = *(const short8*)(smem + boff);
                bl[kc][s] = *(const short8*)(smem + 8192 + boff);
            }
        }
        bool more = (k0 + 64 < Kp);
        if (more) {
            #pragma unroll
            for (int m = 0; m < 4; ++m) {
                int phys = (c4 * 4 + m) ^ (rn & 15);
                float4 v = *(const float4*)(smem + 32768 + rn * 256 + phys * 16);
                vals[m * 4 + 0] = v.x; vals[m * 4 + 1] = v.y;
                vals[m * 4 + 2] = v.z; vals[m * 4 + 3] = v.w;
            }
        }
        __syncthreads();   // (2)
        if (more) {
            #pragma unroll
            for (int i = 0; i < 4; ++i) { gll16(srcs[i], smem + dstoff[i]); srcs[i] += 64; }
            if (k0 + 128 < Kp) {
                #pragma unroll
                for (int i = 0; i < 4; ++i) {
                    int col = k0 + 128 + xcol[i];
                    const float* s = (xrow[i] < NN && col < 500)
                                   ? x + (size_t)xrow[i] * 500 + col : zpad;
                    gll16(s, smem + xdst[i]);
                }
            }
        }
        #pragma unroll
        for (int kc = 0; kc < 2; ++kc)
            #pragma unroll
            for (int s = 0; s < 4; ++s) {
                acc[s] = __builtin_amdgcn_mfma_f32_16x16x32_bf16(al[kc], bh[kc][s], acc[s], 0, 0, 0);
                acc[s] = __builtin_amdgcn_mfma_f32_16x16x32_bf16(ah[kc], bl[kc][s], acc[s], 0, 0, 0);
                acc[s] = __builtin_amdgcn_mfma_f32_16x16x32_bf16(ah[kc], bh[kc][s], acc[s], 0, 0, 0);
            }
    }

    int growb = row0 + w * 16 + q * 4;
    float dgv[4];
    #pragma unroll
    for (int r = 0; r < 4; ++r) {
        int grow = growb + r;
        dgv[r] = (grow < M) ? sdeg[grow - row0] : 0.f;
    }
    #pragma unroll
    for (int s = 0; s < 4; ++s) {
        int gc = col0 + s * 16 + l16;
        float bia = bias[gc];
        float s_sum = 0.f, ss_sum = 0.f;
        #pragma unroll
        for (int r = 0; r < 4; ++r) {
            int grow = growb + r;
            bool real = grow < M;
            float v = fmaxf(fmaf(dgv[r], acc[s][r], bia), 0.f);
            if (!real) v = 0.f;
            s_sum += v; ss_sum += v * v;
            float vo = v * dgv[r];
            u16 h, l; split1(vo, h, l);
            Ohi[(size_t)grow * No + gc] = h;
            Olo[(size_t)grow * No + gc] = l;
        }
        s_sum  += __shfl_xor(s_sum, 16);  s_sum  += __shfl_xor(s_sum, 32);
        ss_sum += __shfl_xor(ss_sum, 16); ss_sum += __shfl_xor(ss_sum, 32);
        if (lane < 16) {
            atomicAdd(&stats[gc], s_sum);
            atomicAdd(&stats[256 + gc], ss_sum);
        }
    }
}

// ---------------- conv1 with in-kernel BN0 fold of W1 (proven r11) ----------------
__global__ __launch_bounds__(256, 4)
void conv1_fold(const u16* __restrict__ Ahi, const u16* __restrict__ Alo,
                const float* __restrict__ W1, const float* __restrict__ stats0,
                const float* __restrict__ g0, const float* __restrict__ bb0,
                const float* __restrict__ b1, const float* __restrict__ degh,
                float* __restrict__ stats1, u16* __restrict__ Ohi, u16* __restrict__ Olo) {
    __shared__ char smem[32768];
    __shared__ float scl[256], sh[256], cred[256], cvec[64];
    const int Kp = 256, M = NN, No = 256;
    const int b = blockIdx.x;
    const int xcd = b & 7, g = b >> 3;
    const int bx = g & 3, by = (g >> 2) * 8 + xcd;
    if (by >= 158) return;
    const int t = threadIdx.x;
    const int lane = t & 63;
    const int w = t >> 6;
    const int q = lane >> 4;
    const int l16 = lane & 15;
    const int m7 = l16 & 7;
    const int row0 = by * 64;
    const int col0 = bx * 64;

    const u16* srcs[4];
    unsigned dstoff[4];
    #pragma unroll
    for (int i = 0; i < 4; ++i) {
        int gi = w + i * 4;
        int plane = gi >> 3, j = gi & 7;
        int r = j * 8 + (lane >> 3);
        int c = (lane & 7) ^ (r & 7);
        srcs[i] = (plane ? Alo : Ahi) + (size_t)(row0 + r) * Kp + c * 8;
        dstoff[i] = plane * 8192 + j * 1024;
    }
    #pragma unroll
    for (int i = 0; i < 4; ++i) { gll16(srcs[i], smem + dstoff[i]); srcs[i] += 64; }

    {
        float mean = stats0[t] * (1.f / NN);
        float var = stats0[256 + t] * (1.f / NN) - mean * mean;
        float s = g0[t] * rsqrtf(var + BN_EPS);
        scl[t] = s;
        sh[t] = bb0[t] - mean * s;
    }
    __syncthreads();
    {
        float s = 0.f;
        int n = col0 + (t & 63);
        #pragma unroll 8
        for (int k = (t >> 6); k < 256; k += 4)
            s += sh[k] * W1[(size_t)k * 256 + n];
        cred[t] = s;
        __syncthreads();
        if (t < 64) cvec[t] = cred[t] + cred[t + 64] + cred[t + 128] + cred[t + 192];
    }
    const int bn = t & 63;
    const int kb = (t >> 6) * 16;
    const int ch0 = (t >> 6) * 2;
    float vals[16];
    {
        const float* wp = W1 + (size_t)kb * 256 + col0 + bn;
        #pragma unroll
        for (int i = 0; i < 16; ++i) vals[i] = wp[(size_t)i * 256] * scl[kb + i];
    }

    f32x4 acc[4];
    #pragma unroll
    for (int s = 0; s < 4; ++s) acc[s] = (f32x4){0.f, 0.f, 0.f, 0.f};

    for (int k0 = 0; k0 < Kp; k0 += 64) {
        {
            u16 hs[16], ls[16];
            #pragma unroll
            for (int i = 0; i < 16; ++i) split1(vals[i], hs[i], ls[i]);
            unsigned o0 = bn * 128 + ((ch0 ^ (bn & 7)) * 16);
            unsigned o1 = bn * 128 + (((ch0 + 1) ^ (bn & 7)) * 16);
            *(short8*)(smem + 16384 + o0) = *(short8*)&hs[0];
            *(short8*)(smem + 16384 + o1) = *(short8*)&hs[8];
            *(short8*)(smem + 24576 + o0) = *(short8*)&ls[0];
            *(short8*)(smem + 24576 + o1) = *(short8*)&ls[8];
        }
        __syncthreads();   // (1)
        short8 ah[2], al[2], bh[2][4], bl[2][4];
        #pragma unroll
        for (int kc = 0; kc < 2; ++kc) {
            int aoff = (w * 16 + l16) * 128 + (((kc * 4 + q) ^ m7) * 16);
            ah[kc] = *(const short8*)(smem + aoff);
            al[kc] = *(const short8*)(smem + 8192 + aoff);
            #pragma unroll
            for (int s = 0; s < 4; ++s) {
                int boff = (s * 16 + l16) * 128 + (((kc * 4 + q) ^ m7) * 16);
                bh[kc][s] = *(const short8*)(smem + 16384 + boff);
                bl[kc][s] = *(const short8*)(smem + 24576 + boff);
            }
        }
        __syncthreads();   // (2)
        if (k0 + 64 < Kp) {
            #pragma unroll
            for (int i = 0; i < 4; ++i) { gll16(srcs[i], smem + dstoff[i]); srcs[i] += 64; }
            const float* wp = W1 + (size_t)(k0 + 64 + kb) * 256 + col0 + bn;
            #pragma unroll
            for (int i = 0; i < 16; ++i) vals[i] = wp[(size_t)i * 256] * scl[k0 + 64 + kb + i];
        }
        #pragma unroll
        for (int kc = 0; kc < 2; ++kc)
            #pragma unroll
            for (int s = 0; s < 4; ++s) {
                acc[s] = __builtin_amdgcn_mfma_f32_16x16x32_bf16(al[kc], bh[kc][s], acc[s], 0, 0, 0);
                acc[s] = __builtin_amdgcn_mfma_f32_16x16x32_bf16(ah[kc], bl[kc][s], acc[s], 0, 0, 0);
                acc[s] = __builtin_amdgcn_mfma_f32_16x16x32_bf16(ah[kc], bh[kc][s], acc[s], 0, 0, 0);
            }
    }

    int growb = row0 + w * 16 + q * 4;
    float dgv[4];
    #pragma unroll
    for (int r = 0; r < 4; ++r) {
        int grow = growb + r;
        dgv[r] = (grow < M) ? (degh[grow] + degh[MP + grow]) : 0.f;
    }
    #pragma unroll
    for (int s = 0; s < 4; ++s) {
        int gc = col0 + s * 16 + l16;
        float bia = b1[gc];
        float cv = cvec[s * 16 + l16];
        float s_sum = 0.f, ss_sum = 0.f;
        #pragma unroll
        for (int r = 0; r < 4; ++r) {
            int grow = growb + r;
            bool real = grow < M;
            float v = fmaxf(fmaf(dgv[r], cv, acc[s][r] + bia), 0.f);
            if (!real) v = 0.f;
            s_sum += v; ss_sum += v * v;
            u16 h, l; split1(v, h, l);
            Ohi[(size_t)grow * No + gc] = h;
            Olo[(size_t)grow * No + gc] = l;
        }
        s_sum  += __shfl_xor(s_sum, 16);  s_sum  += __shfl_xor(s_sum, 32);
        ss_sum += __shfl_xor(ss_sum, 16); ss_sum += __shfl_xor(ss_sum, 32);
        if (lane < 16) {
            atomicAdd(&stats1[gc], s_sum);
            atomicAdd(&stats1[256 + gc], ss_sum);
        }
    }
}

// ---------------- fused fc0 (BN1 fold, 64x128) + in-block fc1 ------------------
// r1-proven body, now at (256,3): LDS 52.5 KB -> 3 blocks/CU (was 2).
__global__ __launch_bounds__(256, 3)
void fc_fused(const u16* __restrict__ Ahi, const u16* __restrict__ Alo,
              const float* __restrict__ fW0, const float* __restrict__ stats1,
              const float* __restrict__ g1, const float* __restrict__ bb1,
              const float* __restrict__ fb0,
              const u16* __restrict__ Whi, const u16* __restrict__ Wlo,
              const float* __restrict__ fb1, float* __restrict__ out) {
    __shared__ char smem[49152];
    __shared__ float scl[256], sh[256], cred[256], biasf[128];
    const int M = NN;
    const int by = blockIdx.x;
    const int t = threadIdx.x;
    const int lane = t & 63;
    const int w = t >> 6;
    const int q = lane >> 4;
    const int l16 = lane & 15;
    const int m7 = l16 & 7;
    const int row0 = by * 64;

    const u16* asrc[4];
    unsigned adst[4];
    #pragma unroll
    for (int i = 0; i < 4; ++i) {
        int gi = w + i * 4;
        int plane = gi >> 3, j = gi & 7;
        int r = j * 8 + (lane >> 3);
        int c = (lane & 7) ^ (r & 7);
        asrc[i] = (plane ? Alo : Ahi) + (size_t)(row0 + r) * 256 + c * 8;
        adst[i] = plane * 8192 + j * 1024;
    }
    #pragma unroll
    for (int i = 0; i < 4; ++i) gll16(asrc[i], smem + adst[i]);   // sub0 k-step 0

    {
        float mean = stats1[t] * (1.f / NN);
        float var = stats1[256 + t] * (1.f / NN) - mean * mean;
        float s = g1[t] * rsqrtf(var + BN_EPS);
        scl[t] = s;
        sh[t] = bb1[t] - mean * s;
    }
    __syncthreads();
    {
        int col = t & 127, half = t >> 7;
        float s = 0.f;
        #pragma unroll 8
        for (int k = half * 128; k < half * 128 + 128; ++k)
            s += sh[k] * fW0[(size_t)k * 128 + col];
        cred[t] = s;
    }
    __syncthreads();
    if (t < 128) biasf[t] = fb0[t] + cred[t] + cred[128 + t];

    const int bn = t & 63;
    const int kb = (t >> 6) * 16;
    const int ch0 = (t >> 6) * 2;

    unsigned h3p[2][16];   // packed (hi<<16)|lo per relu output
    f32x4 acc[4];

    #pragma unroll
    for (int sub = 0; sub < 2; ++sub) {
        if (sub) {
            #pragma unroll
            for (int i = 0; i < 4; ++i) { asrc[i] -= 192; gll16(asrc[i], smem + adst[i]); }
        }
        float vals[16];
        {
            const float* wp = fW0 + (size_t)kb * 128 + sub * 64 + bn;
            #pragma unroll
            for (int i = 0; i < 16; ++i) vals[i] = wp[(size_t)i * 128] * scl[kb + i];
        }
        #pragma unroll
        for (int s = 0; s < 4; ++s) acc[s] = (f32x4){0.f, 0.f, 0.f, 0.f};

        for (int k0 = 0; k0 < 256; k0 += 64) {
            {
                u16 hs[16], ls[16];
                #pragma unroll
                for (int i = 0; i < 16; ++i) split1(vals[i], hs[i], ls[i]);
                unsigned o0 = bn * 128 + ((ch0 ^ (bn & 7)) * 16);
                unsigned o1 = bn * 128 + (((ch0 + 1) ^ (bn & 7)) * 16);
                *(short8*)(smem + 16384 + o0) = *(short8*)&hs[0];
                *(short8*)(smem + 16384 + o1) = *(short8*)&hs[8];
                *(short8*)(smem + 24576 + o0) = *(short8*)&ls[0];
                *(short8*)(smem + 24576 + o1) = *(short8*)&ls[8];
            }
            __syncthreads();   // (1)
            short8 ah[2], al[2], bh[2][4], bl[2][4];
            #pragma unroll
            for (int kc = 0; kc < 2; ++kc) {
                int aoff = (w * 16 + l16) * 128 + (((kc * 4 + q) ^ m7) * 16);
                ah[kc] = *(const short8*)(smem + aoff);
                al[kc] = *(const short8*)(smem + 8192 + aoff);
                #pragma unroll
                for (int s = 0; s < 4; ++s) {
                    int boff = (s * 16 + l16) * 128 + (((kc * 4 + q) ^ m7) * 16);
                    bh[kc][s] = *(const short8*)(smem + 16384 + boff);
                    bl[kc][s] = *(const short8*)(smem + 24576 + boff);
                }
            }
            __syncthreads();   // (2)
            if (k0 + 64 < 256) {
                #pragma unroll
                for (int i = 0; i < 4; ++i) { asrc[i] += 64; gll16(asrc[i], smem + adst[i]); }
                const float* wp = fW0 + (size_t)(k0 + 64 + kb) * 128 + sub * 64 + bn;
                #pragma unroll
                for (int i = 0; i < 16; ++i) vals[i] = wp[(size_t)i * 128] * scl[k0 + 64 + kb + i];
            }
            #pragma unroll
            for (int kc = 0; kc < 2; ++kc)
                #pragma unroll
                for (int s = 0; s < 4; ++s) {
                    acc[s] = __builtin_amdgcn_mfma_f32_16x16x32_bf16(al[kc], bh[kc][s], acc[s], 0, 0, 0);
                    acc[s] = __builtin_amdgcn_mfma_f32_16x16x32_bf16(ah[kc], bl[kc][s], acc[s], 0, 0, 0);
                    acc[s] = __builtin_amdgcn_mfma_f32_16x16x32_bf16(ah[kc], bh[kc][s], acc[s], 0, 0, 0);
                }
        }

        {
            int growb = row0 + w * 16 + q * 4;
            #pragma unroll
            for (int s = 0; s < 4; ++s) {
                float bia = biasf[sub * 64 + s * 16 + l16];
                #pragma unroll
                for (int r = 0; r < 4; ++r) {
                    float v = fmaxf(acc[s][r] + bia, 0.f);
                    if (growb + r >= M) v = 0.f;
                    u16 h, l; split1(v, h, l);
                    h3p[sub][s * 4 + r] = ((unsigned)h << 16) | l;
                }
            }
        }
    }

    // issue fc1 B staging, k-step 0 (region1 — untouched so far)
    #pragma unroll
    for (int i = 0; i < 4; ++i) {
        int gi = w + i * 4;
        int plane = gi >> 3, j = gi & 7;
        int r = j * 8 + (lane >> 3);
        int c = (lane & 7) ^ (r & 7);
        const u16* s = (plane ? Wlo : Whi) + (size_t)r * 128 + c * 8;
        gll16(s, smem + 32768 + plane * 8192 + j * 1024);
    }

    // write h3 into region0 in the fc1 A-frag layout
    {
        int rl0 = w * 16 + q * 4;
        #pragma unroll
        for (int sub = 0; sub < 2; ++sub)
            #pragma unroll
            for (int s = 0; s < 4; ++s)
                #pragma unroll
                for (int r = 0; r < 4; ++r) {
                    int rl = rl0 + r;
                    int kk = s * 16 + l16;            // k within step
                    int j = kk >> 3;
                    unsigned off = (unsigned)sub * 8192 + rl * 128 +
                                   ((j ^ (rl & 7)) * 16) + (kk & 7) * 2;
                    unsigned pv = h3p[sub][s * 4 + r];
                    *(u16*)(smem + off) = (u16)(pv >> 16);
                    *(u16*)(smem + 16384 + off) = (u16)pv;
                }
    }

    #pragma unroll
    for (int s = 0; s < 4; ++s) acc[s] = (f32x4){0.f, 0.f, 0.f, 0.f};

    __syncthreads();   // h3 visible; fc1 B st0 vmcnt drained

    #pragma unroll
    for (int st = 0; st < 2; ++st) {
        short8 ah[2], al[2], bh[2][4], bl[2][4];
        #pragma unroll
        for (int kc = 0; kc < 2; ++kc) {
            int aoff = st * 8192 + (w * 16 + l16) * 128 + (((kc * 4 + q) ^ m7) * 16);
            ah[kc] = *(const short8*)(smem + aoff);
            al[kc] = *(const short8*)(smem + 16384 + aoff);
            #pragma unroll
            for (int s = 0; s < 4; ++s) {
                int boff = 32768 + (s * 16 + l16) * 128 + (((kc * 4 + q) ^ m7) * 16);
                bh[kc][s] = *(const short8*)(smem + boff);
                bl[kc][s] = *(const short8*)(smem + 8192 + boff);
            }
        }
        __syncthreads();   // all reads of region1 done before restage
        if (st == 0) {
            #pragma unroll
            for (int i = 0; i < 4; ++i) {
                int gi = w + i * 4;
                int plane = gi >> 3, j = gi & 7;
                int r = j * 8 + (lane >> 3);
                int c = (lane & 7) ^ (r & 7);
                const u16* s = (plane ? Wlo : Whi) + (size_t)r * 128 + 64 + c * 8;
                gll16(s, smem + 32768 + plane * 8192 + j * 1024);
            }
        }
        #pragma unroll
        for (int kc = 0; kc < 2; ++kc)
            #pragma unroll
            for (int s = 0; s < 4; ++s) {
                acc[s] = __builtin_amdgcn_mfma_f32_16x16x32_bf16(al[kc], bh[kc][s], acc[s], 0, 0, 0);
                acc[s] = __builtin_amdgcn_mfma_f32_16x16x32_bf16(ah[kc], bl[kc][s], acc[s], 0, 0, 0);
                acc[s] = __builtin_amdgcn_mfma_f32_16x16x32_bf16(ah[kc], bh[kc][s], acc[s], 0, 0, 0);
            }
        if (st == 0) __syncthreads();   // fc1 B st1 ready
    }

    {
        int growb = row0 + w * 16 + q * 4;
        #pragma unroll
        for (int s = 0; s < 4; ++s) {
            int gc = s * 16 + l16;
            if (gc >= 40) continue;
            float bia = fb1[gc];
            #pragma unroll
            for (int r = 0; r < 4; ++r) {
                int grow = growb + r;
                if (grow < M)
                    out[(size_t)grow * 40 + gc] = fmaxf(acc[s][r] + bia, 0.f);
            }
        }
    }
}

// ---------------- launch ----------------

extern "C" void kernel_launch(void* const* d_in, const int* in_sizes, int n_in,
                              void* d_out, int out_size, void* d_ws, size_t ws_size,
                              hipStream_t stream) {
    const float* x   = (const float*)d_in[0];
    const int*   ei  = (const int*)d_in[1];
    const float* W0  = (const float*)d_in[2];
    const float* b0  = (const float*)d_in[3];
    const float* g0  = (const float*)d_in[4];
    const float* bb0 = (const float*)d_in[5];
    const float* W1  = (const float*)d_in[6];
    const float* b1  = (const float*)d_in[7];
    const float* g1  = (const float*)d_in[8];
    const float* bb1 = (const float*)d_in[9];
    const float* fW0 = (const float*)d_in[10];
    const float* fb0 = (const float*)d_in[11];
    const float* fW1 = (const float*)d_in[12];
    const float* fb1 = (const float*)d_in[13];
    float* out = (float*)d_out;

    char* ws = (char*)d_ws;
    auto carve = [&](size_t bytes) { char* q = ws; ws += (bytes + 255) & ~(size_t)255; return q; };

    float* stats = (float*)carve(4096);        // zeroed by degree_prep blocks 160/161
    float* zpad  = (float*)carve(1024);        // zeroed by degree_prep block 160
    unsigned* cnts = (unsigned*)carve((size_t)NBUCK * 64 * 4);          // fully written
    float* degh = (float*)carve((size_t)2 * MP * 4);                    // fully written
    unsigned* bucketArr = (unsigned*)carve((size_t)NBUCK * 64 * SUBCAP * 4);  // 4 MB
    u16* W0t    = (u16*)carve((size_t)2 * 256 * 512 * 2);
    u16* fW1t   = (u16*)carve((size_t)2 * 64 * 128 * 2);
    u16* H1     = (u16*)carve((size_t)2 * MP * 256 * 2);
    u16* H2     = (u16*)carve((size_t)2 * MP * 256 * 2);

    dim3 blk(256);

    // 1. bucketize edges (the only producer phase 2's degree blocks wait on)
    edge_bucketize<<<64, blk, 0, stream>>>(ei, bucketArr, cnts);
    // 2. degree (LDS-bitmap dedup) ∥ W0/fW1 splits ∥ stats/zpad zero
    degree_prep<<<162, blk, 0, stream>>>(bucketArr, cnts, degh, stats, zpad,
                                         W0, fW1, W0t, fW1t);
    // 3. conv0 (x staged to LDS via gll16 with pre-swizzled source)
    conv0_gemm<<<640, blk, 0, stream>>>(
        x, zpad, W0t, W0t + 256 * 512, degh, b0, stats, H1, H1 + (size_t)MP * 256);
    // 4. conv1 (self-folds BN0 into W1; swizzled)
    conv1_fold<<<640, blk, 0, stream>>>(
        H1, H1 + (size_t)MP * 256, W1, stats, g0, bb0, b1, degh,
        stats + 512, H2, H2 + (size_t)MP * 256);
    // 5. fused fc0+fc1 at 3 blocks/CU (H3 stays in LDS/registers)
    fc_fused<<<157, blk, 0, stream>>>(
        H2, H2 + (size_t)MP * 256, fW0, stats + 512, g1, bb1, fb0,
        fW1t, fW1t + 64 * 128, fb1, out);
}

// Round 9
// 177.077 us; speedup vs baseline: 2.4613x; 1.0249x over previous
//
#include <hip/hip_runtime.h>

#define NN 10000
#define NE 320000
#define MP 10112        // 158*64 padded rows
#define BN_EPS 1e-5f

#define NRANGE 64       // row-ranges (160 rows each)
#define BROWS 160
#define NBUCK 128       // row-range x j-half buckets
#define HBITS 5120      // bits per j-half
#define HWORDS 160      // words per j-half row
#define SUBCAP 128      // keys per (bucket, block) sub-chunk (mean ~39)
#define EPB   5000      // edges per bucketize block (64*5000 = NE exact)

typedef __attribute__((ext_vector_type(8))) short short8;
typedef __attribute__((ext_vector_type(4))) float f32x4;
typedef unsigned short u16;

// ---------------- helpers ----------------
__device__ __forceinline__ void split1(float v, u16& h, u16& l) {
    unsigned int u = __float_as_uint(v);
    h = (u16)(u >> 16);
    float hf = __uint_as_float(u & 0xFFFF0000u);
    l = (u16)(__float_as_uint(v - hf) >> 16);
}

__device__ __forceinline__ void gll16(const void* g, void* l) {
    __builtin_amdgcn_global_load_lds(
        (const __attribute__((address_space(1))) unsigned int*)g,
        (__attribute__((address_space(3))) unsigned int*)l, 16, 0, 0);
}

// ---------------- splitW (proven): Wt[n][k] = split(W[k][n]) ----------------
__device__ void splitW_dev(const float* __restrict__ W, int K, int N, int Kp, int Np,
                           u16* __restrict__ Wt, int bx, int by, char* smem) {
    float (*tile)[65] = (float(*)[65])smem;
    int t = threadIdx.x;
    int bk = bx * 64, bn = by * 64;
    #pragma unroll
    for (int p = 0; p < 4; ++p) {
        int kk = (t >> 4) + p * 16;
        int nc = (t & 15) * 4;
        int k = bk + kk;
        float4 v = {0.f, 0.f, 0.f, 0.f};
        if (k < K && bn + nc + 3 < N)
            v = *(const float4*)&W[(size_t)k * N + bn + nc];
        tile[kk][nc] = v.x; tile[kk][nc + 1] = v.y;
        tile[kk][nc + 2] = v.z; tile[kk][nc + 3] = v.w;
    }
    __syncthreads();
    int nn = t >> 2;
    int kk0 = (t & 3) * 16;
    u16 hs[16], ls[16];
    #pragma unroll
    for (int j = 0; j < 16; ++j) split1(tile[kk0 + j][nn], hs[j], ls[j]);
    size_t ob = (size_t)(bn + nn) * Kp + bk + kk0;
    size_t lo = (size_t)Np * Kp;
    *(short8*)&Wt[ob] = *(short8*)hs;
    *(short8*)&Wt[ob + 8] = *(short8*)&hs[8];
    *(short8*)&Wt[lo + ob] = *(short8*)ls;
    *(short8*)&Wt[lo + ob + 8] = *(short8*)&ls[8];
}

// ---------------- scatter_prep: bucketize + weight splits + stats/zpad zero ----
// [0,64): edge bucketize into fixed per-(bucket,block) sub-chunks;
// [64,96): W0 split; [96,98): fW1 split + stats/zpad zero.
__global__ __launch_bounds__(256)
void scatter_prep(const int* __restrict__ ei,
                  unsigned* __restrict__ bucketArr, unsigned* __restrict__ cnts,
                  float* __restrict__ stats, float* __restrict__ zpad,
                  const float* __restrict__ W0, const float* __restrict__ fW1,
                  u16* __restrict__ W0t, u16* __restrict__ fW1t) {
    __shared__ char smem[16704];
    __shared__ unsigned cnt[NBUCK];
    int b = blockIdx.x;
    int t = threadIdx.x;
    if (b < 64) {
        if (t < NBUCK) cnt[t] = 0;
        __syncthreads();
        int base = b * EPB;
        #pragma unroll
        for (int k = 0; k < 20; ++k) {
            int el = t + k * 256;
            if (el < EPB) {
                int e = base + el;
                unsigned i = (unsigned)ei[e], j = (unsigned)ei[NE + e];
                unsigned bk = (i / BROWS) * 2 + (j >= HBITS ? 1u : 0u);
                unsigned key = (i << 14) | j;
                unsigned pos = atomicAdd(&cnt[bk], 1u);
                if (pos < SUBCAP)
                    bucketArr[((size_t)bk << 13) + ((unsigned)b << 7) + pos] = key;
            }
        }
        __syncthreads();
        if (t < NBUCK) cnts[(t << 6) + b] = min(cnt[t], (unsigned)SUBCAP);
    } else if (b < 96) {
        int idx = b - 64;
        splitW_dev(W0, 500, 256, 512, 256, W0t, idx & 7, idx >> 3, smem);
    } else {
        int base = (b - 96) * 512;
        stats[base + t] = 0.f;
        stats[base + 256 + t] = 0.f;
        if (b == 96 && t < 64) zpad[t] = 0.f;
        splitW_dev(fW1, 128, 40, 128, 64, fW1t, b - 96, 0, smem);
    }
}

// ---------------- bucket_degree: LDS-bitmap dedup + popcount -> degh -----------
__global__ __launch_bounds__(256)
void bucket_degree(const unsigned* __restrict__ bucketArr,
                   const unsigned* __restrict__ cnts,
                   float* __restrict__ degh) {
    __shared__ unsigned lbm[BROWS * HWORDS];   // 102,400 B
    int b = blockIdx.x, t = threadIdx.x;
    int rr = b >> 1, h = b & 1;
    int row0 = rr * BROWS;
    {
        uint4* z = (uint4*)lbm;
        #pragma unroll
        for (int i = 0; i < 25; ++i) z[t + i * 256] = (uint4){0u, 0u, 0u, 0u};
    }
    __syncthreads();
    for (int r = t; r < BROWS; r += 256) {
        int i = row0 + r;
        if (i < NN && ((i >= HBITS) == (h == 1))) {
            int jj = i - h * HBITS;
            atomicOr(&lbm[r * HWORDS + (jj >> 5)], 1u << (jj & 31));
        }
    }
    {
        int sb = t >> 2, kl = t & 3;
        unsigned n = cnts[(b << 6) + sb];
        const unsigned* keys = bucketArr + ((size_t)b << 13) + ((unsigned)sb << 7);
        for (unsigned k = kl; k < n; k += 4) {
            unsigned key = keys[k];
            unsigned i = key >> 14, j = key & 0x3FFFu;
            unsigned r = i - row0;
            unsigned jj = j - h * HBITS;
            atomicOr(&lbm[r * HWORDS + (jj >> 5)], 1u << (jj & 31));
        }
    }
    __syncthreads();
    #pragma unroll
    for (int pass = 0; pass < 3; ++pass) {
        int r = pass * 64 + (t >> 2), wl = t & 3;
        if (r >= BROWS) break;
        int i = row0 + r;
        int c = 0;
        const uint4* rp = (const uint4*)&lbm[r * HWORDS + wl * 40];
        #pragma unroll
        for (int m = 0; m < 10; ++m) {
            uint4 v = rp[m];
            c += __popc(v.x) + __popc(v.y) + __popc(v.z) + __popc(v.w);
        }
        c += __shfl_down(c, 1, 4);
        c += __shfl_down(c, 2, 4);
        if (wl == 0 && i < MP) degh[h * MP + i] = (float)c;
    }
}

// ---------------- conv0 GEMM (verified r6): x staged to LDS via gll16 ----------
__global__ __launch_bounds__(256, 3)
void conv0_gemm(const float* __restrict__ x, const float* __restrict__ zpad,
                const u16* __restrict__ Bhi, const u16* __restrict__ Blo,
                const float* __restrict__ degh, const float* __restrict__ bias,
                float* __restrict__ stats,
                u16* __restrict__ Ohi, u16* __restrict__ Olo) {
    __shared__ char smem[49152];
    __shared__ float sdeg[64];
    const int Kp = 512, M = NN, No = 256;
    const int b = blockIdx.x;
    const int xcd = b & 7, g = b >> 3;
    const int bx = g & 3, by = (g >> 2) * 8 + xcd;
    if (by >= 158) return;
    const int t = threadIdx.x;
    const int lane = t & 63;
    const int w = t >> 6;
    const int q = lane >> 4;
    const int l16 = lane & 15;
    const int m7 = l16 & 7;
    const int row0 = by * 64;
    const int col0 = bx * 64;

    const u16* srcs[4];
    unsigned dstoff[4];
    #pragma unroll
    for (int i = 0; i < 4; ++i) {
        int j = w + (i & 1) * 4;
        int plane = i >> 1;
        int r = j * 8 + (lane >> 3);
        int c = (lane & 7) ^ (r & 7);
        srcs[i] = (plane ? Blo : Bhi) + (size_t)(col0 + r) * Kp + c * 8;
        dstoff[i] = 16384 + plane * 8192 + j * 1024;
    }

    int xrow[4];
    int xcol[4];
    unsigned xdst[4];
    #pragma unroll
    for (int i = 0; i < 4; ++i) {
        int slab = w * 4 + i;
        int row = slab * 4 + (lane >> 4);
        int cl = (lane & 15) ^ (row & 15);
        xrow[i] = row0 + row;
        xcol[i] = cl * 4;
        xdst[i] = 32768 + slab * 1024;
    }

    #pragma unroll
    for (int i = 0; i < 4; ++i) gll16(srcs[i], smem + dstoff[i]);
    #pragma unroll
    for (int i = 0; i < 4; ++i) {
        int col = xcol[i];
        const float* s = (xrow[i] < NN && col < 500)
                       ? x + (size_t)xrow[i] * 500 + col : zpad;
        gll16(s, smem + xdst[i]);
    }

    if (t < 64) sdeg[t] = degh[row0 + t] + degh[MP + row0 + t];

    __syncthreads();   // X(0), B(0) resident

    const int rn = t & 63;
    const int c4 = t >> 6;
    const int ch0 = c4 * 2;
    float vals[16];
    #pragma unroll
    for (int m = 0; m < 4; ++m) {
        int phys = (c4 * 4 + m) ^ (rn & 15);
        float4 v = *(const float4*)(smem + 32768 + rn * 256 + phys * 16);
        vals[m * 4 + 0] = v.x; vals[m * 4 + 1] = v.y;
        vals[m * 4 + 2] = v.z; vals[m * 4 + 3] = v.w;
    }

    __syncthreads();   // all X(0) reads done

    #pragma unroll
    for (int i = 0; i < 4; ++i) {
        int col = 64 + xcol[i];
        const float* s = (xrow[i] < NN && col < 500)
                       ? x + (size_t)xrow[i] * 500 + col : zpad;
        gll16(s, smem + xdst[i]);
    }
    #pragma unroll
    for (int i = 0; i < 4; ++i) srcs[i] += 64;

    f32x4 acc[4];
    #pragma unroll
    for (int s = 0; s < 4; ++s) acc[s] = (f32x4){0.f, 0.f, 0.f, 0.f};

    for (int k0 = 0; k0 < Kp; k0 += 64) {
        {
            u16 hs[16], ls[16];
            #pragma unroll
            for (int i2 = 0; i2 < 16; ++i2) split1(vals[i2], hs[i2], ls[i2]);
            unsigned o0 = rn * 128 + ((ch0 ^ (rn & 7)) * 16);
            unsigned o1 = rn * 128 + (((ch0 + 1) ^ (rn & 7)) * 16);
            *(short8*)(smem + o0) = *(short8*)&hs[0];
            *(short8*)(smem + o1) = *(short8*)&hs[8];
            *(short8*)(smem + 8192 + o0) = *(short8*)&ls[0];
            *(short8*)(smem + 8192 + o1) = *(short8*)&ls[8];
        }
        __syncthreads();   // (1)
        short8 ah[2], al[2], bh[2][4], bl[2][4];
        #pragma unroll
        for (int kc = 0; kc < 2; ++kc) {
            int aoff = (w * 16 + l16) * 128 + (((kc * 4 + q) ^ m7) * 16);
            ah[kc] = *(const short8*)(smem + aoff);
            al[kc] = *(const short8*)(smem + 8192 + aoff);
            #pragma unroll
            for (int s = 0; s < 4; ++s) {
                int boff = 16384 + (s * 16 + l16) * 128 + (((kc * 4 + q) ^ m7) * 16);
                bh[kc][s] = *(const short8*)(smem + boff);
                bl[kc][s] = *(const short8*)(smem + 8192 + boff);
            }
        }
        bool more = (k0 + 64 < Kp);
        if (more) {
            #pragma unroll
            for (int m = 0; m < 4; ++m) {
                int phys = (c4 * 4 + m) ^ (rn & 15);
                float4 v = *(const float4*)(smem + 32768 + rn * 256 + phys * 16);
                vals[m * 4 + 0] = v.x; vals[m * 4 + 1] = v.y;
                vals[m * 4 + 2] = v.z; vals[m * 4 + 3] = v.w;
            }
        }
        __syncthreads();   // (2)
        if (more) {
            #pragma unroll
            for (int i = 0; i < 4; ++i) { gll16(srcs[i], smem + dstoff[i]); srcs[i] += 64; }
            if (k0 + 128 < Kp) {
                #pragma unroll
                for (int i = 0; i < 4; ++i) {
                    int col = k0 + 128 + xcol[i];
                    const float* s = (xrow[i] < NN && col < 500)
                                   ? x + (size_t)xrow[i] * 500 + col : zpad;
                    gll16(s, smem + xdst[i]);
                }
            }
        }
        #pragma unroll
        for (int kc = 0; kc < 2; ++kc)
            #pragma unroll
            for (int s = 0; s < 4; ++s) {
                acc[s] = __builtin_amdgcn_mfma_f32_16x16x32_bf16(al[kc], bh[kc][s], acc[s], 0, 0, 0);
                acc[s] = __builtin_amdgcn_mfma_f32_16x16x32_bf16(ah[kc], bl[kc][s], acc[s], 0, 0, 0);
                acc[s] = __builtin_amdgcn_mfma_f32_16x16x32_bf16(ah[kc], bh[kc][s], acc[s], 0, 0, 0);
            }
    }

    int growb = row0 + w * 16 + q * 4;
    float dgv[4];
    #pragma unroll
    for (int r = 0; r < 4; ++r) {
        int grow = growb + r;
        dgv[r] = (grow < M) ? sdeg[grow - row0] : 0.f;
    }
    #pragma unroll
    for (int s = 0; s < 4; ++s) {
        int gc = col0 + s * 16 + l16;
        float bia = bias[gc];
        float s_sum = 0.f, ss_sum = 0.f;
        #pragma unroll
        for (int r = 0; r < 4; ++r) {
            int grow = growb + r;
            bool real = grow < M;
            float v = fmaxf(fmaf(dgv[r], acc[s][r], bia), 0.f);
            if (!real) v = 0.f;
            s_sum += v; ss_sum += v * v;
            float vo = v * dgv[r];
            u16 h, l; split1(vo, h, l);
            Ohi[(size_t)grow * No + gc] = h;
            Olo[(size_t)grow * No + gc] = l;
        }
        s_sum  += __shfl_xor(s_sum, 16);  s_sum  += __shfl_xor(s_sum, 32);
        ss_sum += __shfl_xor(ss_sum, 16); ss_sum += __shfl_xor(ss_sum, 32);
        if (lane < 16) {
            atomicAdd(&stats[gc], s_sum);
            atomicAdd(&stats[256 + gc], ss_sum);
        }
    }
}

// ---------------- conv1 with in-kernel BN0 fold of W1 (r6 + vals prefetch) -----
// Change vs r6: next K-step's folded-W loads issue BEFORE barrier (1) (prefetch
// distance += frag-read phase + 2 barriers); values bit-identical.
__global__ __launch_bounds__(256, 4)
void conv1_fold(const u16* __restrict__ Ahi, const u16* __restrict__ Alo,
                const float* __restrict__ W1, const float* __restrict__ stats0,
                const float* __restrict__ g0, const float* __restrict__ bb0,
                const float* __restrict__ b1, const float* __restrict__ degh,
                float* __restrict__ stats1, u16* __restrict__ Ohi, u16* __restrict__ Olo) {
    __shared__ char smem[32768];
    __shared__ float scl[256], sh[256], cred[256], cvec[64];
    const int Kp = 256, M = NN, No = 256;
    const int b = blockIdx.x;
    const int xcd = b & 7, g = b >> 3;
    const int bx = g & 3, by = (g >> 2) * 8 + xcd;
    if (by >= 158) return;
    const int t = threadIdx.x;
    const int lane = t & 63;
    const int w = t >> 6;
    const int q = lane >> 4;
    const int l16 = lane & 15;
    const int m7 = l16 & 7;
    const int row0 = by * 64;
    const int col0 = bx * 64;

    const u16* srcs[4];
    unsigned dstoff[4];
    #pragma unroll
    for (int i = 0; i < 4; ++i) {
        int gi = w + i * 4;
        int plane = gi >> 3, j = gi & 7;
        int r = j * 8 + (lane >> 3);
        int c = (lane & 7) ^ (r & 7);
        srcs[i] = (plane ? Alo : Ahi) + (size_t)(row0 + r) * Kp + c * 8;
        dstoff[i] = plane * 8192 + j * 1024;
    }
    #pragma unroll
    for (int i = 0; i < 4; ++i) { gll16(srcs[i], smem + dstoff[i]); srcs[i] += 64; }

    {
        float mean = stats0[t] * (1.f / NN);
        float var = stats0[256 + t] * (1.f / NN) - mean * mean;
        float s = g0[t] * rsqrtf(var + BN_EPS);
        scl[t] = s;
        sh[t] = bb0[t] - mean * s;
    }
    __syncthreads();
    {
        float s = 0.f;
        int n = col0 + (t & 63);
        #pragma unroll 8
        for (int k = (t >> 6); k < 256; k += 4)
            s += sh[k] * W1[(size_t)k * 256 + n];
        cred[t] = s;
        __syncthreads();
        if (t < 64) cvec[t] = cred[t] + cred[t + 64] + cred[t + 128] + cred[t + 192];
    }
    const int bn = t & 63;
    const int kb = (t >> 6) * 16;
    const int ch0 = (t >> 6) * 2;
    float vals[16];
    {
        const float* wp = W1 + (size_t)kb * 256 + col0 + bn;
        #pragma unroll
        for (int i = 0; i < 16; ++i) vals[i] = wp[(size_t)i * 256] * scl[kb + i];
    }

    f32x4 acc[4];
    #pragma unroll
    for (int s = 0; s < 4; ++s) acc[s] = (f32x4){0.f, 0.f, 0.f, 0.f};

    for (int k0 = 0; k0 < Kp; k0 += 64) {
        {
            u16 hs[16], ls[16];
            #pragma unroll
            for (int i = 0; i < 16; ++i) split1(vals[i], hs[i], ls[i]);
            unsigned o0 = bn * 128 + ((ch0 ^ (bn & 7)) * 16);
            unsigned o1 = bn * 128 + (((ch0 + 1) ^ (bn & 7)) * 16);
            *(short8*)(smem + 16384 + o0) = *(short8*)&hs[0];
            *(short8*)(smem + 16384 + o1) = *(short8*)&hs[8];
            *(short8*)(smem + 24576 + o0) = *(short8*)&ls[0];
            *(short8*)(smem + 24576 + o1) = *(short8*)&ls[8];
        }
        bool more = (k0 + 64 < Kp);
        float valsn[16];
        if (more) {   // PREFETCH: issued ~2 barriers + frag-read phase early
            const float* wp = W1 + (size_t)(k0 + 64 + kb) * 256 + col0 + bn;
            #pragma unroll
            for (int i = 0; i < 16; ++i) valsn[i] = wp[(size_t)i * 256] * scl[k0 + 64 + kb + i];
        }
        __syncthreads();   // (1)
        short8 ah[2], al[2], bh[2][4], bl[2][4];
        #pragma unroll
        for (int kc = 0; kc < 2; ++kc) {
            int aoff = (w * 16 + l16) * 128 + (((kc * 4 + q) ^ m7) * 16);
            ah[kc] = *(const short8*)(smem + aoff);
            al[kc] = *(const short8*)(smem + 8192 + aoff);
            #pragma unroll
            for (int s = 0; s < 4; ++s) {
                int boff = (s * 16 + l16) * 128 + (((kc * 4 + q) ^ m7) * 16);
                bh[kc][s] = *(const short8*)(smem + 16384 + boff);
                bl[kc][s] = *(const short8*)(smem + 24576 + boff);
            }
        }
        __syncthreads();   // (2)
        if (more) {
            #pragma unroll
            for (int i = 0; i < 4; ++i) { gll16(srcs[i], smem + dstoff[i]); srcs[i] += 64; }
        }
        #pragma unroll
        for (int kc = 0; kc < 2; ++kc)
            #pragma unroll
            for (int s = 0; s < 4; ++s) {
                acc[s] = __builtin_amdgcn_mfma_f32_16x16x32_bf16(al[kc], bh[kc][s], acc[s], 0, 0, 0);
                acc[s] = __builtin_amdgcn_mfma_f32_16x16x32_bf16(ah[kc], bl[kc][s], acc[s], 0, 0, 0);
                acc[s] = __builtin_amdgcn_mfma_f32_16x16x32_bf16(ah[kc], bh[kc][s], acc[s], 0, 0, 0);
            }
        if (more) {
            #pragma unroll
            for (int i = 0; i < 16; ++i) vals[i] = valsn[i];
        }
    }

    int growb = row0 + w * 16 + q * 4;
    float dgv[4];
    #pragma unroll
    for (int r = 0; r < 4; ++r) {
        int grow = growb + r;
        dgv[r] = (grow < M) ? (degh[grow] + degh[MP + grow]) : 0.f;
    }
    #pragma unroll
    for (int s = 0; s < 4; ++s) {
        int gc = col0 + s * 16 + l16;
        float bia = b1[gc];
        float cv = cvec[s * 16 + l16];
        float s_sum = 0.f, ss_sum = 0.f;
        #pragma unroll
        for (int r = 0; r < 4; ++r) {
            int grow = growb + r;
            bool real = grow < M;
            float v = fmaxf(fmaf(dgv[r], cv, acc[s][r] + bia), 0.f);
            if (!real) v = 0.f;
            s_sum += v; ss_sum += v * v;
            u16 h, l; split1(v, h, l);
            Ohi[(size_t)grow * No + gc] = h;
            Olo[(size_t)grow * No + gc] = l;
        }
        s_sum  += __shfl_xor(s_sum, 16);  s_sum  += __shfl_xor(s_sum, 32);
        ss_sum += __shfl_xor(ss_sum, 16); ss_sum += __shfl_xor(ss_sum, 32);
        if (lane < 16) {
            atomicAdd(&stats1[gc], s_sum);
            atomicAdd(&stats1[256 + gc], ss_sum);
        }
    }
}

// ---------------- fc0 with in-kernel BN1 fold of fW0 (r6 + vals prefetch) ------
__global__ __launch_bounds__(256, 4)
void fc0_fold(const u16* __restrict__ Ahi, const u16* __restrict__ Alo,
              const float* __restrict__ fW0, const float* __restrict__ stats1,
              const float* __restrict__ g1, const float* __restrict__ bb1,
              const float* __restrict__ fb0,
              u16* __restrict__ Ohi, u16* __restrict__ Olo) {
    __shared__ char smem[32768];
    __shared__ float scl[256], sh[256], cred[256], biasf[64];
    const int Kp = 256, M = NN, No = 128;
    const int b = blockIdx.x;
    const int xcd = b & 7, g = b >> 3;
    const int bx = g & 1, by = (g >> 1) * 8 + xcd;
    if (by >= 158) return;
    const int t = threadIdx.x;
    const int lane = t & 63;
    const int w = t >> 6;
    const int q = lane >> 4;
    const int l16 = lane & 15;
    const int m7 = l16 & 7;
    const int row0 = by * 64;
    const int col0 = bx * 64;

    const u16* srcs[4];
    unsigned dstoff[4];
    #pragma unroll
    for (int i = 0; i < 4; ++i) {
        int gi = w + i * 4;
        int plane = gi >> 3, j = gi & 7;
        int r = j * 8 + (lane >> 3);
        int c = (lane & 7) ^ (r & 7);
        srcs[i] = (plane ? Alo : Ahi) + (size_t)(row0 + r) * Kp + c * 8;
        dstoff[i] = plane * 8192 + j * 1024;
    }
    #pragma unroll
    for (int i = 0; i < 4; ++i) { gll16(srcs[i], smem + dstoff[i]); srcs[i] += 64; }

    {
        float mean = stats1[t] * (1.f / NN);
        float var = stats1[256 + t] * (1.f / NN) - mean * mean;
        float s = g1[t] * rsqrtf(var + BN_EPS);
        scl[t] = s;
        sh[t] = bb1[t] - mean * s;
    }
    __syncthreads();
    {
        float s = 0.f;
        int n = col0 + (t & 63);
        #pragma unroll 8
        for (int k = (t >> 6); k < 256; k += 4)
            s += sh[k] * fW0[(size_t)k * 128 + n];
        cred[t] = s;
        __syncthreads();
        if (t < 64)
            biasf[t] = fb0[col0 + t] + cred[t] + cred[t + 64] + cred[t + 128] + cred[t + 192];
    }
    const int bn = t & 63;
    const int kb = (t >> 6) * 16;
    const int ch0 = (t >> 6) * 2;
    float vals[16];
    {
        const float* wp = fW0 + (size_t)kb * 128 + col0 + bn;
        #pragma unroll
        for (int i = 0; i < 16; ++i) vals[i] = wp[(size_t)i * 128] * scl[kb + i];
    }

    f32x4 acc[4];
    #pragma unroll
    for (int s = 0; s < 4; ++s) acc[s] = (f32x4){0.f, 0.f, 0.f, 0.f};

    for (int k0 = 0; k0 < Kp; k0 += 64) {
        {
            u16 hs[16], ls[16];
            #pragma unroll
            for (int i = 0; i < 16; ++i) split1(vals[i], hs[i], ls[i]);
            unsigned o0 = bn * 128 + ((ch0 ^ (bn & 7)) * 16);
            unsigned o1 = bn * 128 + (((ch0 + 1) ^ (bn & 7)) * 16);
            *(short8*)(smem + 16384 + o0) = *(short8*)&hs[0];
            *(short8*)(smem + 16384 + o1) = *(short8*)&hs[8];
            *(short8*)(smem + 24576 + o0) = *(short8*)&ls[0];
            *(short8*)(smem + 24576 + o1) = *(short8*)&ls[8];
        }
        bool more = (k0 + 64 < Kp);
        float valsn[16];
        if (more) {   // PREFETCH (see conv1_fold)
            const float* wp = fW0 + (size_t)(k0 + 64 + kb) * 128 + col0 + bn;
            #pragma unroll
            for (int i = 0; i < 16; ++i) valsn[i] = wp[(size_t)i * 128] * scl[k0 + 64 + kb + i];
        }
        __syncthreads();   // (1)
        short8 ah[2], al[2], bh[2][4], bl[2][4];
        #pragma unroll
        for (int kc = 0; kc < 2; ++kc) {
            int aoff = (w * 16 + l16) * 128 + (((kc * 4 + q) ^ m7) * 16);
            ah[kc] = *(const short8*)(smem + aoff);
            al[kc] = *(const short8*)(smem + 8192 + aoff);
            #pragma unroll
            for (int s = 0; s < 4; ++s) {
                int boff = (s * 16 + l16) * 128 + (((kc * 4 + q) ^ m7) * 16);
                bh[kc][s] = *(const short8*)(smem + 16384 + boff);
                bl[kc][s] = *(const short8*)(smem + 24576 + boff);
            }
        }
        __syncthreads();   // (2)
        if (more) {
            #pragma unroll
            for (int i = 0; i < 4; ++i) { gll16(srcs[i], smem + dstoff[i]); srcs[i] += 64; }
        }
        #pragma unroll
        for (int kc = 0; kc < 2; ++kc)
            #pragma unroll
            for (int s = 0; s < 4; ++s) {
                acc[s] = __builtin_amdgcn_mfma_f32_16x16x32_bf16(al[kc], bh[kc][s], acc[s], 0, 0, 0);
                acc[s] = __builtin_amdgcn_mfma_f32_16x16x32_bf16(ah[kc], bl[kc][s], acc[s], 0, 0, 0);
                acc[s] = __builtin_amdgcn_mfma_f32_16x16x32_bf16(ah[kc], bh[kc][s], acc[s], 0, 0, 0);
            }
        if (more) {
            #pragma unroll
            for (int i = 0; i < 16; ++i) vals[i] = valsn[i];
        }
    }

    int growb = row0 + w * 16 + q * 4;
    #pragma unroll
    for (int s = 0; s < 4; ++s) {
        int gc = col0 + s * 16 + l16;
        float bia = biasf[s * 16 + l16];
        #pragma unroll
        for (int r = 0; r < 4; ++r) {
            int grow = growb + r;
            float v = fmaxf(acc[s][r] + bia, 0.f);
            if (grow >= M) v = 0.f;
            u16 h, l; split1(v, h, l);
            Ohi[(size_t)grow * No + gc] = h;
            Olo[(size_t)grow * No + gc] = l;
        }
    }
}

// ---------------- fc1 (proven): Kp=128, N=40, fp32 out ----------------
__global__ __launch_bounds__(256, 3)
void fc1_gemm(const u16* __restrict__ Ahi, const u16* __restrict__ Alo,
              const u16* __restrict__ Bhi, const u16* __restrict__ Blo,
              const float* __restrict__ bias, float* __restrict__ out) {
    __shared__ char smem[32768];
    const int Kp = 128, M = NN, N = 40, No = 40;
    const int t = threadIdx.x;
    const int lane = t & 63;
    const int w = t >> 6;
    const int q = lane >> 4;
    const int l16 = lane & 15;
    const int m7 = l16 & 7;
    const int row0 = blockIdx.x * 64;
    const int col0 = 0;

    const u16* bases[4] = {Ahi, Alo, Bhi, Blo};
    const u16* srcs[8];
    unsigned dstoff[8];
    #pragma unroll
    for (int i = 0; i < 8; ++i) {
        int gi = w + i * 4;
        int reg = i >> 1;
        int j = gi & 7;
        int rb = (reg < 2) ? row0 : col0;
        int r = j * 8 + (lane >> 3);
        int c = (lane & 7) ^ (r & 7);
        srcs[i] = bases[reg] + (size_t)(rb + r) * Kp + c * 8;
        dstoff[i] = reg * 8192 + j * 1024;
    }

    f32x4 acc[4];
    #pragma unroll
    for (int s = 0; s < 4; ++s) acc[s] = (f32x4){0.f, 0.f, 0.f, 0.f};

    #pragma unroll
    for (int i = 0; i < 8; ++i) { gll16(srcs[i], smem + dstoff[i]); srcs[i] += 64; }

    for (int k0 = 0; k0 < Kp; k0 += 64) {
        __syncthreads();
        short8 ah[2], al[2], bh[2][4], bl[2][4];
        #pragma unroll
        for (int kc = 0; kc < 2; ++kc) {
            int aoff = (w * 16 + l16) * 128 + (((kc * 4 + q) ^ m7) * 16);
            ah[kc] = *(const short8*)(smem + aoff);
            al[kc] = *(const short8*)(smem + 8192 + aoff);
            #pragma unroll
            for (int s = 0; s < 4; ++s) {
                int boff = (s * 16 + l16) * 128 + (((kc * 4 + q) ^ m7) * 16);
                bh[kc][s] = *(const short8*)(smem + 16384 + boff);
                bl[kc][s] = *(const short8*)(smem + 24576 + boff);
            }
        }
        __syncthreads();
        if (k0 + 64 < Kp) {
            #pragma unroll
            for (int i = 0; i < 8; ++i) { gll16(srcs[i], smem + dstoff[i]); srcs[i] += 64; }
        }
        #pragma unroll
        for (int kc = 0; kc < 2; ++kc)
            #pragma unroll
            for (int s = 0; s < 4; ++s) {
                acc[s] = __builtin_amdgcn_mfma_f32_16x16x32_bf16(al[kc], bh[kc][s], acc[s], 0, 0, 0);
                acc[s] = __builtin_amdgcn_mfma_f32_16x16x32_bf16(ah[kc], bl[kc][s], acc[s], 0, 0, 0);
                acc[s] = __builtin_amdgcn_mfma_f32_16x16x32_bf16(ah[kc], bh[kc][s], acc[s], 0, 0, 0);
            }
    }

    int growb = row0 + w * 16 + q * 4;
    #pragma unroll
    for (int s = 0; s < 4; ++s) {
        int gc = col0 + s * 16 + l16;
        if (gc >= N) continue;
        float bia = bias[gc];
        #pragma unroll
        for (int r = 0; r < 4; ++r) {
            int grow = growb + r;
            if (grow < M)
                out[(size_t)grow * No + gc] = fmaxf(acc[s][r] + bia, 0.f);
        }
    }
}

// ---------------- launch ----------------

extern "C" void kernel_launch(void* const* d_in, const int* in_sizes, int n_in,
                              void* d_out, int out_size, void* d_ws, size_t ws_size,
                              hipStream_t stream) {
    const float* x   = (const float*)d_in[0];
    const int*   ei  = (const int*)d_in[1];
    const float* W0  = (const float*)d_in[2];
    const float* b0  = (const float*)d_in[3];
    const float* g0  = (const float*)d_in[4];
    const float* bb0 = (const float*)d_in[5];
    const float* W1  = (const float*)d_in[6];
    const float* b1  = (const float*)d_in[7];
    const float* g1  = (const float*)d_in[8];
    const float* bb1 = (const float*)d_in[9];
    const float* fW0 = (const float*)d_in[10];
    const float* fb0 = (const float*)d_in[11];
    const float* fW1 = (const float*)d_in[12];
    const float* fb1 = (const float*)d_in[13];
    float* out = (float*)d_out;

    char* ws = (char*)d_ws;
    auto carve = [&](size_t bytes) { char* q = ws; ws += (bytes + 255) & ~(size_t)255; return q; };

    float* stats = (float*)carve(4096);        // zeroed by scatter_prep blocks 96/97
    float* zpad  = (float*)carve(1024);        // zeroed by scatter_prep block 96
    unsigned* cnts = (unsigned*)carve((size_t)NBUCK * 64 * 4);          // fully written
    float* degh = (float*)carve((size_t)2 * MP * 4);                    // fully written
    unsigned* bucketArr = (unsigned*)carve((size_t)NBUCK * 64 * SUBCAP * 4);  // 4 MB
    u16* W0t    = (u16*)carve((size_t)2 * 256 * 512 * 2);
    u16* fW1t   = (u16*)carve((size_t)2 * 64 * 128 * 2);
    u16* H1     = (u16*)carve((size_t)2 * MP * 256 * 2);
    u16* H2     = (u16*)carve((size_t)2 * MP * 256 * 2);
    u16* H3     = (u16*)carve((size_t)2 * MP * 128 * 2);

    dim3 blk(256);

    // 1. bucketize edges + split W0/fW1 + zero stats/zpad (r6 overlap preserved)
    scatter_prep<<<98, blk, 0, stream>>>(ei, bucketArr, cnts, stats, zpad, W0, fW1, W0t, fW1t);
    // 2. LDS-bitmap dedup + popcount -> degh
    bucket_degree<<<NBUCK, blk, 0, stream>>>(bucketArr, cnts, degh);
    // 3. conv0 (x staged to LDS via gll16 with pre-swizzled source)
    conv0_gemm<<<640, blk, 0, stream>>>(
        x, zpad, W0t, W0t + 256 * 512, degh, b0, stats, H1, H1 + (size_t)MP * 256);
    // 4. conv1 (self-folds BN0 into W1; vals prefetched one step deep)
    conv1_fold<<<640, blk, 0, stream>>>(
        H1, H1 + (size_t)MP * 256, W1, stats, g0, bb0, b1, degh,
        stats + 512, H2, H2 + (size_t)MP * 256);
    // 5. fc0 (self-folds BN1 into fW0; vals prefetched one step deep)
    fc0_fold<<<320, blk, 0, stream>>>(
        H2, H2 + (size_t)MP * 256, fW0, stats + 512, g1, bb1, fb0,
        H3, H3 + (size_t)MP * 128);
    // 6. fc1
    fc1_gemm<<<158, blk, 0, stream>>>(
        H3, H3 + (size_t)MP * 128, fW1t, fW1t + 64 * 128, fb1, out);
}